// Round 9
// baseline (723.019 us; speedup 1.0000x reference)
//
#include <hip/hip_runtime.h>
#include <math.h>

#define NROWS 4096

// ws float offsets
#define WS_Q    0u          // 4096*64 q
#define WS_K    262144u     // 4096*64 k
#define WS_RS   524288u     // 4096 row sums
#define WS_GPRE 528384u     // 4096*4
#define WS_X    544768u     // 4096*64 embedded x
#define BUFA    1048576u    // 4096*4096
#define BUFB    17825792u   // 4096*4096
#define WS_NEED 34603008u   // floats = 138.4 MB (proven to fit in R7)

static __device__ __forceinline__ float preluf(float x, float a) {
    return x > 0.0f ? x : a * x;
}

// ---------------------------------------------------------------------------
__global__ __launch_bounds__(256) void beacon(float* __restrict__ out, float v) {
    int i = blockIdx.x * 256 + threadIdx.x;
    if (i < NROWS * 4) out[i] = v;
}

// K0: zero RS + GPRE (contiguous 20480 floats)
__global__ __launch_bounds__(256) void zero_rs(float* __restrict__ ws) {
    int i = blockIdx.x * 256 + threadIdx.x;
    if (i < 20480) ws[WS_RS + i] = 0.0f;
}

// ---------------------------------------------------------------------------
// K1a: x = in@We + be   (4096x8 @ 8x64) ; thread = (row, h)
// ---------------------------------------------------------------------------
__global__ __launch_bounds__(256) void embed_x(
    const float* __restrict__ in, const float* __restrict__ We,
    const float* __restrict__ be, float* __restrict__ ws)
{
    int gid = blockIdx.x * 256 + threadIdx.x;   // 262144 total
    int i = gid >> 6, h = gid & 63;
    float s = be[h];
    #pragma unroll
    for (int d = 0; d < 8; ++d) s += in[(size_t)i * 8 + d] * We[d * 64 + h];
    ws[WS_X + gid] = s;
}

// ---------------------------------------------------------------------------
// K1b: q = x@Wq+bq ; k = x@Wk+bk  (64x64 each); thread = (row, h)
// ---------------------------------------------------------------------------
__global__ __launch_bounds__(256) void qk_proj(
    const float* __restrict__ Wq, const float* __restrict__ bq,
    const float* __restrict__ Wk, const float* __restrict__ bk,
    float* __restrict__ ws)
{
    int gid = blockIdx.x * 256 + threadIdx.x;
    int i = gid >> 6, h = gid & 63;
    const float* x = ws + WS_X + (size_t)i * 64;
    float sq = bq[h], sk = bk[h];
    for (int d = 0; d < 64; ++d) {
        float xv = x[d];
        sq += xv * Wq[d * 64 + h];
        sk += xv * Wk[d * 64 + h];
    }
    ws[WS_Q + gid] = sq;
    ws[WS_K + gid] = sk;
}

// ---------------------------------------------------------------------------
// K2: 64x64 score tiles: e = exp(q.k/8) -> BUFA (unnormalized), rowsum atomics.
// ---------------------------------------------------------------------------
__global__ __launch_bounds__(256) void scores_tile(float* __restrict__ ws)
{
    __shared__ float qs[64][65];
    __shared__ float ks[64][65];
    const int br = blockIdx.y * 64, bc = blockIdx.x * 64;
    const int t = threadIdx.x;
    for (int idx = t; idx < 4096; idx += 256) {
        int r = idx >> 6, d = idx & 63;
        qs[r][d] = ws[WS_Q + (size_t)(br + r) * 64 + d];
        ks[r][d] = ws[WS_K + (size_t)(bc + r) * 64 + d];
    }
    __syncthreads();
    const int rg = t >> 6, j = t & 63;   // wave = fixed rg, 64 j lanes
    #pragma unroll 1
    for (int rr = 0; rr < 16; ++rr) {
        const int r = rg * 16 + rr;
        float d = 0.0f;
        #pragma unroll
        for (int dd = 0; dd < 64; ++dd) d += qs[r][dd] * ks[j][dd];
        float e = expf(d * 0.125f);
        ws[BUFA + (size_t)(br + r) * NROWS + bc + j] = e;
        float red = e;
        #pragma unroll
        for (int off = 1; off < 64; off <<= 1) red += __shfl_xor(red, off);
        if (j == 0) atomicAdd(&ws[WS_RS + br + r], red);
    }
}

// ---------------------------------------------------------------------------
// K2b: normalize scores in place (divide to match reference)
// ---------------------------------------------------------------------------
__global__ __launch_bounds__(256) void normalize_k(float* __restrict__ ws)
{
    const int i = blockIdx.y;
    const int j = blockIdx.x * 256 + threadIdx.x;
    const size_t idx = BUFA + (size_t)i * NROWS + j;
    ws[idx] = ws[idx] / ws[WS_RS + i];
}

// ---------------------------------------------------------------------------
// K4: one global stencil iteration, zero padding.
// ---------------------------------------------------------------------------
__global__ __launch_bounds__(256) void stencil_k(
    const float* __restrict__ src, float* __restrict__ dst,
    const float* __restrict__ c1k, const float* __restrict__ c1b,
    const float* __restrict__ c2k, const float* __restrict__ c2b,
    const float* __restrict__ pa)
{
    const int i = blockIdx.y;
    const int j = blockIdx.x * 256 + threadIdx.x;
    const size_t idx = (size_t)i * NROWS + j;
    const float c  = src[idx];
    const float lf = (j > 0)         ? src[idx - 1]     : 0.0f;
    const float rt = (j < NROWS - 1) ? src[idx + 1]     : 0.0f;
    const float up = (i > 0)         ? src[idx - NROWS] : 0.0f;
    const float dn = (i < NROWS - 1) ? src[idx + NROWS] : 0.0f;
    const float rowv = c1k[0] * lf + c1k[1] * c + c1k[2] * rt + c1b[0];
    const float colv = c2k[0] * up + c2k[1] * c + c2k[2] * dn + c2b[0];
    dst[idx] = preluf(rowv + colv, pa[0]);
}

// ---------------------------------------------------------------------------
// K5: gpre[i][c] = (1/rs_i) * sum_j [cf_ij>0] * exp(q_i.k_j/8) * o_jc
// block = 64 rows x 512 j (8 chunks of 64); cf read from BUFA.
// ---------------------------------------------------------------------------
__global__ __launch_bounds__(256) void adj_o(
    const float* __restrict__ in, float* __restrict__ ws)
{
    __shared__ float qs[64][65];
    __shared__ float ks[64][65];
    __shared__ float os[64][5];
    const int br = blockIdx.y * 64;
    const int jb = blockIdx.x * 512;
    const int t = threadIdx.x;
    for (int idx = t; idx < 4096; idx += 256) {
        int r = idx >> 6, d = idx & 63;
        qs[r][d] = ws[WS_Q + (size_t)(br + r) * 64 + d];
    }
    const int rg = t >> 6, j = t & 63;
    float acc[16][4];
    #pragma unroll
    for (int rr = 0; rr < 16; ++rr) {
        #pragma unroll
        for (int c = 0; c < 4; ++c) acc[rr][c] = 0.0f;
    }
    for (int ch = 0; ch < 8; ++ch) {
        const int c0 = jb + ch * 64;
        __syncthreads();
        for (int idx = t; idx < 4096; idx += 256) {
            int jj = idx >> 6, d = idx & 63;
            ks[jj][d] = ws[WS_K + (size_t)(c0 + jj) * 64 + d];
        }
        {
            int jj = t >> 2, c = t & 3;
            os[jj][c] = in[(size_t)(c0 + jj) * 8 + c];
        }
        __syncthreads();
        #pragma unroll 1
        for (int rr = 0; rr < 16; ++rr) {
            const int r = rg * 16 + rr;
            float cf = ws[BUFA + (size_t)(br + r) * NROWS + c0 + j];
            if (cf > 0.0f) {
                float d = 0.0f;
                #pragma unroll
                for (int dd = 0; dd < 64; ++dd) d += qs[r][dd] * ks[j][dd];
                float e = expf(d * 0.125f);
                acc[rr][0] += e * os[j][0];
                acc[rr][1] += e * os[j][1];
                acc[rr][2] += e * os[j][2];
                acc[rr][3] += e * os[j][3];
            }
        }
    }
    #pragma unroll 1
    for (int rr = 0; rr < 16; ++rr) {
        const int row = br + rg * 16 + rr;
        float v[4];
        #pragma unroll
        for (int c = 0; c < 4; ++c) {
            float red = acc[rr][c];
            #pragma unroll
            for (int off = 1; off < 64; off <<= 1) red += __shfl_xor(red, off);
            v[c] = red;
        }
        if (j == 0) {
            float il = 1.0f / ws[WS_RS + row];
            #pragma unroll
            for (int c = 0; c < 4; ++c)
                atomicAdd(&ws[WS_GPRE + row * 4 + c], v[c] * il);
        }
    }
}

// ---------------------------------------------------------------------------
// K6: head — g = prelu(gpre@Wg(4x64)+bg); pred = relu(g@Wp1(64x32)+bp1)@Wp2+bp2
// ---------------------------------------------------------------------------
__global__ __launch_bounds__(256) void head(
    const float* __restrict__ ws,
    const float* __restrict__ Wg, const float* __restrict__ bg, const float* __restrict__ ga,
    const float* __restrict__ Wp1, const float* __restrict__ bp1,
    const float* __restrict__ Wp2, const float* __restrict__ bp2,
    float* __restrict__ out)
{
    int i = blockIdx.x * 256 + threadIdx.x;
    if (i >= NROWS) return;
    const float a = ga[0];
    float gp[4];
    #pragma unroll
    for (int c = 0; c < 4; ++c) gp[c] = ws[WS_GPRE + (size_t)i * 4 + c];
    float p1[32];
    #pragma unroll
    for (int m = 0; m < 32; ++m) p1[m] = bp1[m];
    for (int h = 0; h < 64; ++h) {
        float s = bg[h];
        #pragma unroll
        for (int c = 0; c < 4; ++c) s += gp[c] * Wg[c * 64 + h];
        float gh = preluf(s, a);
        #pragma unroll
        for (int m = 0; m < 32; ++m) p1[m] += gh * Wp1[h * 32 + m];
    }
    float s0 = bp2[0], s1 = bp2[1], s2 = bp2[2], s3 = bp2[3];
    #pragma unroll
    for (int m = 0; m < 32; ++m) {
        float pm = fmaxf(p1[m], 0.0f);
        s0 += pm * Wp2[m * 4 + 0];
        s1 += pm * Wp2[m * 4 + 1];
        s2 += pm * Wp2[m * 4 + 2];
        s3 += pm * Wp2[m * 4 + 3];
    }
    float4 ov; ov.x = s0; ov.y = s1; ov.z = s2; ov.w = s3;
    *reinterpret_cast<float4*>(out + (size_t)i * 4) = ov;
}

// ---------------------------------------------------------------------------
// K7: audit — NaN -> 2^38 beacon; dead (max|gpre|<1e-8) -> 2^36. Else silent.
// ---------------------------------------------------------------------------
__global__ __launch_bounds__(256) void audit(
    const float* __restrict__ ws, float* __restrict__ out)
{
    __shared__ float red[256];
    const int t = threadIdx.x;
    float mx = 0.0f;
    for (int i = t; i < NROWS * 4; i += 256) {
        float v = ws[WS_GPRE + i];
        if (v != v) mx = 1e30f;
        else mx = fmaxf(mx, fabsf(v));
    }
    red[t] = mx;
    __syncthreads();
    for (int s = 128; s > 0; s >>= 1) {
        if (t < s) red[t] = fmaxf(red[t], red[t + s]);
        __syncthreads();
    }
    const float g = red[0];
    float V = 0.0f;
    if (g >= 1e29f)      V = ldexpf(1.0f, 38);
    else if (g <= 1e-8f) V = ldexpf(1.0f, 36);
    if (V != 0.0f) {
        for (int i = t; i < NROWS * 4; i += 256) out[i] = V;
    }
}

// ---------------------------------------------------------------------------
extern "C" void kernel_launch(void* const* d_in, const int* in_sizes, int n_in,
                              void* d_out, int out_size, void* d_ws, size_t ws_size,
                              hipStream_t stream) {
    float* out = (float*)d_out;
    float* ws  = (float*)d_ws;

    // Correct dict-order sizes for N=4096, D=8, H=64, O=4
    static const int dict_sizes[19] = {32768, 512, 64, 4096, 64, 4096, 64,
                                       1, 3, 1, 3, 1, 256, 64, 1, 2048, 32, 128, 4};
    if (n_in != 19) {
        beacon<<<64, 256, 0, stream>>>(out, ldexpf(1.0f + (float)n_in / 256.0f, 40));
        return;
    }
    bool is_dict = true;
    for (int i = 0; i < 19; ++i) if (in_sizes[i] != dict_sizes[i]) is_dict = false;
    if (!is_dict) {
        // encode log2(in_sizes[1]), log2(in_sizes[2]) in mantissa
        int l1 = 0, l2 = 0;
        while ((1 << (l1 + 1)) <= in_sizes[1] && l1 < 15) ++l1;
        while ((1 << (l2 + 1)) <= in_sizes[2] && l2 < 15) ++l2;
        beacon<<<64, 256, 0, stream>>>(out, ldexpf(1.0f + (float)(l1 * 16 + l2) / 256.0f, 42));
        return;
    }
    if (out_size != NROWS * 4) {
        beacon<<<64, 256, 0, stream>>>(out, ldexpf(1.0f, 44));
        return;
    }
    if (ws_size < (size_t)WS_NEED * sizeof(float)) {
        beacon<<<64, 256, 0, stream>>>(out, ldexpf(1.0f, 46));
        return;
    }

    const float* in   = (const float*)d_in[0];
    const float* We   = (const float*)d_in[1];
    const float* be   = (const float*)d_in[2];
    const float* Wq   = (const float*)d_in[3];
    const float* bq   = (const float*)d_in[4];
    const float* Wk   = (const float*)d_in[5];
    const float* bk   = (const float*)d_in[6];
    const float* pa   = (const float*)d_in[7];
    const float* c1k  = (const float*)d_in[8];
    const float* c1b  = (const float*)d_in[9];
    const float* c2k  = (const float*)d_in[10];
    const float* c2b  = (const float*)d_in[11];
    const float* Wg   = (const float*)d_in[12];
    const float* bg   = (const float*)d_in[13];
    const float* ga   = (const float*)d_in[14];
    const float* Wp1  = (const float*)d_in[15];
    const float* bp1  = (const float*)d_in[16];
    const float* Wp2  = (const float*)d_in[17];
    const float* bp2  = (const float*)d_in[18];

    zero_rs<<<80, 256, 0, stream>>>(ws);
    embed_x<<<1024, 256, 0, stream>>>(in, We, be, ws);
    qk_proj<<<1024, 256, 0, stream>>>(Wq, bq, Wk, bk, ws);

    dim3 gt(64, 64);
    scores_tile<<<gt, 256, 0, stream>>>(ws);
    dim3 gn(16, NROWS);
    normalize_k<<<gn, 256, 0, stream>>>(ws);

    float* A = ws + BUFA;
    float* B = ws + BUFB;
    float* cur = A;
    float* oth = B;
    for (int it = 0; it < 10; ++it) {
        stencil_k<<<gn, 256, 0, stream>>>(cur, oth, c1k, c1b, c2k, c2b, pa);
        float* tmp = cur; cur = oth; oth = tmp;
    }
    // cur == A after 10 iterations; BUFA holds cf

    dim3 ga2(8, 64);
    adj_o<<<ga2, 256, 0, stream>>>(in, ws);
    head<<<16, 256, 0, stream>>>(ws, Wg, bg, ga, Wp1, bp1, Wp2, bp2, out);
    audit<<<1, 256, 0, stream>>>(ws, out);
}

// Round 10
// 583.992 us; speedup vs baseline: 1.2381x; 1.2381x over previous
//
#include <hip/hip_runtime.h>
#include <math.h>

#define NROWS 4096

// ws float offsets
#define WS_Q    0u          // 4096*64 q
#define WS_K    262144u     // 4096*64 k
#define WS_RS   524288u     // 4096 row sums
#define WS_GPRE 528384u     // 4096*4
#define WS_X    544768u     // 4096*64 embedded x
#define BUFME   1048576u    // 4096*4096 masked*normalized scores (output of stencil)
#define BUFE    17825792u   // 4096*4096 unnormalized exp scores E
#define WS_NEED 34603008u   // floats = 138.4 MB (fits; proven in R7-R9)

static __device__ __forceinline__ float preluf(float x, float a) {
    return x > 0.0f ? x : a * x;
}

// ---------------------------------------------------------------------------
__global__ __launch_bounds__(256) void beacon(float* __restrict__ out, float v) {
    int i = blockIdx.x * 256 + threadIdx.x;
    if (i < NROWS * 4) out[i] = v;
}

// K0: zero RS + GPRE (contiguous 20480 floats)
__global__ __launch_bounds__(256) void zero_rs(float* __restrict__ ws) {
    int i = blockIdx.x * 256 + threadIdx.x;
    if (i < 20480) ws[WS_RS + i] = 0.0f;
}

// ---------------------------------------------------------------------------
// K1a: x = in@We + be   (4096x8 @ 8x64) ; thread = (row, h)
// ---------------------------------------------------------------------------
__global__ __launch_bounds__(256) void embed_x(
    const float* __restrict__ in, const float* __restrict__ We,
    const float* __restrict__ be, float* __restrict__ ws)
{
    int gid = blockIdx.x * 256 + threadIdx.x;   // 262144 total
    int i = gid >> 6, h = gid & 63;
    float s = be[h];
    #pragma unroll
    for (int d = 0; d < 8; ++d) s += in[(size_t)i * 8 + d] * We[d * 64 + h];
    ws[WS_X + gid] = s;
}

// ---------------------------------------------------------------------------
// K1b: q = x@Wq+bq ; k = x@Wk+bk  (64x64 each); thread = (row, h)
// ---------------------------------------------------------------------------
__global__ __launch_bounds__(256) void qk_proj(
    const float* __restrict__ Wq, const float* __restrict__ bq,
    const float* __restrict__ Wk, const float* __restrict__ bk,
    float* __restrict__ ws)
{
    int gid = blockIdx.x * 256 + threadIdx.x;
    int i = gid >> 6, h = gid & 63;
    const float* x = ws + WS_X + (size_t)i * 64;
    float sq = bq[h], sk = bk[h];
    for (int d = 0; d < 64; ++d) {
        float xv = x[d];
        sq += xv * Wq[d * 64 + h];
        sk += xv * Wk[d * 64 + h];
    }
    ws[WS_Q + gid] = sq;
    ws[WS_K + gid] = sk;
}

// ---------------------------------------------------------------------------
// K2: 64x64 tiles: E = exp(q.k/8) -> BUFE (unnormalized), rowsum atomics.
// ---------------------------------------------------------------------------
__global__ __launch_bounds__(256) void scores_tile(float* __restrict__ ws)
{
    __shared__ float qs[64][65];
    __shared__ float ks[64][65];
    const int br = blockIdx.y * 64, bc = blockIdx.x * 64;
    const int t = threadIdx.x;
    for (int idx = t; idx < 4096; idx += 256) {
        int r = idx >> 6, d = idx & 63;
        qs[r][d] = ws[WS_Q + (size_t)(br + r) * 64 + d];
        ks[r][d] = ws[WS_K + (size_t)(bc + r) * 64 + d];
    }
    __syncthreads();
    const int rg = t >> 6, j = t & 63;
    #pragma unroll 1
    for (int rr = 0; rr < 16; ++rr) {
        const int r = rg * 16 + rr;
        float d = 0.0f;
        #pragma unroll
        for (int dd = 0; dd < 64; ++dd) d += qs[r][dd] * ks[j][dd];
        float e = expf(d * 0.125f);
        ws[BUFE + (size_t)(br + r) * NROWS + bc + j] = e;
        float red = e;
        #pragma unroll
        for (int off = 1; off < 64; off <<= 1) red += __shfl_xor(red, off);
        if (j == 0) atomicAdd(&ws[WS_RS + br + r], red);
    }
}

// ---------------------------------------------------------------------------
// K3: fused 10-iteration stencil per 64x64 tile (halo 10).
// Loads E*il (84x84 halo, zero outside matrix) into LDS, stashes core scores
// in registers, runs 10 ping-pong iterations over the fixed [1,82]^2 region,
// then writes ME = (sigmoid(cf)>0.5) ? score : 0 for the 64x64 core.
// Exactness: after iter t, cells with buffer-margin >= t are exact; garbage
// (incl. uninitialized buf[1] ring) reaches margin-10 core only at t=11.
// ---------------------------------------------------------------------------
__global__ __launch_bounds__(256) void fused_stencil10(
    const float* __restrict__ c1k, const float* __restrict__ c1b,
    const float* __restrict__ c2k, const float* __restrict__ c2b,
    const float* __restrict__ pa, float* __restrict__ ws)
{
    const int r0 = blockIdx.y * 64, c0 = blockIdx.x * 64;
    const int t = threadIdx.x;
    __shared__ float buf[2][84][85];
    __shared__ float il_s[84];

    for (int e = t; e < 84; e += 256) {
        int gr = r0 - 10 + e;
        il_s[e] = ((unsigned)gr < (unsigned)NROWS) ? 1.0f / ws[WS_RS + gr] : 0.0f;
    }
    __syncthreads();

    for (int e = t; e < 84 * 84; e += 256) {
        int ri = e / 84, ci = e - ri * 84;
        int gr = r0 - 10 + ri, gc = c0 - 10 + ci;
        float v = 0.0f;
        if ((unsigned)gr < (unsigned)NROWS && (unsigned)gc < (unsigned)NROWS)
            v = ws[BUFE + (size_t)gr * NROWS + gc] * il_s[ri];
        buf[0][ri][ci] = v;
    }
    __syncthreads();

    // stash normalized core scores (16 cells/thread, static indexing)
    float sc[16];
    #pragma unroll
    for (int k2 = 0; k2 < 16; ++k2) {
        int e = k2 * 256 + t;
        int r = e >> 6, c = e & 63;
        sc[k2] = buf[0][10 + r][10 + c];
    }

    const float k10 = c1k[0], k11 = c1k[1], k12 = c1k[2], b1 = c1b[0];
    const float k20 = c2k[0], k21 = c2k[1], k22 = c2k[2], b2 = c2b[0];
    const float a = pa[0];

    int cur = 0;
    for (int it = 0; it < 10; ++it) {
        int nxt = cur ^ 1;
        for (int e = t; e < 82 * 82; e += 256) {
            int ri = 1 + e / 82;
            int ci = 1 + (e - (e / 82) * 82);
            float c_ = buf[cur][ri][ci];
            float lf = buf[cur][ri][ci - 1];
            float rt = buf[cur][ri][ci + 1];
            float up = buf[cur][ri - 1][ci];
            float dn = buf[cur][ri + 1][ci];
            float s = preluf(k10 * lf + k11 * c_ + k12 * rt + b1 +
                             k20 * up + k21 * c_ + k22 * dn + b2, a);
            int gr = r0 - 10 + ri, gc = c0 - 10 + ci;
            bool inm = ((unsigned)gr < (unsigned)NROWS) && ((unsigned)gc < (unsigned)NROWS);
            buf[nxt][ri][ci] = inm ? s : 0.0f;
        }
        __syncthreads();
        cur = nxt;
    }

    #pragma unroll
    for (int k2 = 0; k2 < 16; ++k2) {
        int e = k2 * 256 + t;
        int r = e >> 6, c = e & 63;
        float cf = buf[cur][10 + r][10 + c];
        float ex = expf(-cf);
        float sg = 1.0f / (1.0f + ex);
        float me = (sg > 0.5f) ? sc[k2] : 0.0f;
        ws[BUFME + (size_t)(r0 + r) * NROWS + (c0 + c)] = me;
    }
}

// ---------------------------------------------------------------------------
// K4: gpre[i][c] = sum_j ME[i][j] * o[j][c] — pure streaming reduction.
// grid (16 col-chunks x 64 row-blocks); block: 64 rows x 256 cols.
// ---------------------------------------------------------------------------
__global__ __launch_bounds__(256) void adj_me(
    const float* __restrict__ in, float* __restrict__ ws)
{
    const int br = blockIdx.y * 64;
    const int jb = blockIdx.x * 256;
    const int t = threadIdx.x;
    __shared__ float os[64][5];
    const int rg = t >> 6, j = t & 63;

    float a0[16], a1[16], a2[16], a3[16];
    #pragma unroll
    for (int rr = 0; rr < 16; ++rr) { a0[rr]=0.f; a1[rr]=0.f; a2[rr]=0.f; a3[rr]=0.f; }

    for (int ch = 0; ch < 4; ++ch) {
        const int c0 = jb + ch * 64;
        __syncthreads();
        { int jj = t >> 2, c = t & 3; os[jj][c] = in[(size_t)(c0 + jj) * 8 + c]; }
        __syncthreads();
        const int rbase = br + rg * 16;
        #pragma unroll
        for (int rr = 0; rr < 16; ++rr) {
            float me = ws[BUFME + (size_t)(rbase + rr) * NROWS + c0 + j];
            a0[rr] += me * os[j][0];
            a1[rr] += me * os[j][1];
            a2[rr] += me * os[j][2];
            a3[rr] += me * os[j][3];
        }
    }
    #pragma unroll
    for (int rr = 0; rr < 16; ++rr) {
        float v0 = a0[rr], v1 = a1[rr], v2 = a2[rr], v3 = a3[rr];
        #pragma unroll
        for (int off = 1; off < 64; off <<= 1) {
            v0 += __shfl_xor(v0, off);
            v1 += __shfl_xor(v1, off);
            v2 += __shfl_xor(v2, off);
            v3 += __shfl_xor(v3, off);
        }
        if (j == 0) {
            const int row = br + rg * 16 + rr;
            atomicAdd(&ws[WS_GPRE + (size_t)row * 4 + 0], v0);
            atomicAdd(&ws[WS_GPRE + (size_t)row * 4 + 1], v1);
            atomicAdd(&ws[WS_GPRE + (size_t)row * 4 + 2], v2);
            atomicAdd(&ws[WS_GPRE + (size_t)row * 4 + 3], v3);
        }
    }
}

// ---------------------------------------------------------------------------
// K5: head — g = prelu(gpre@Wg(4x64)+bg); pred = relu(g@Wp1(64x32)+bp1)@Wp2+bp2
// ---------------------------------------------------------------------------
__global__ __launch_bounds__(256) void head(
    const float* __restrict__ ws,
    const float* __restrict__ Wg, const float* __restrict__ bg, const float* __restrict__ ga,
    const float* __restrict__ Wp1, const float* __restrict__ bp1,
    const float* __restrict__ Wp2, const float* __restrict__ bp2,
    float* __restrict__ out)
{
    int i = blockIdx.x * 256 + threadIdx.x;
    if (i >= NROWS) return;
    const float a = ga[0];
    float gp[4];
    #pragma unroll
    for (int c = 0; c < 4; ++c) gp[c] = ws[WS_GPRE + (size_t)i * 4 + c];
    float p1[32];
    #pragma unroll
    for (int m = 0; m < 32; ++m) p1[m] = bp1[m];
    for (int h = 0; h < 64; ++h) {
        float s = bg[h];
        #pragma unroll
        for (int c = 0; c < 4; ++c) s += gp[c] * Wg[c * 64 + h];
        float gh = preluf(s, a);
        #pragma unroll
        for (int m = 0; m < 32; ++m) p1[m] += gh * Wp1[h * 32 + m];
    }
    float s0 = bp2[0], s1 = bp2[1], s2 = bp2[2], s3 = bp2[3];
    #pragma unroll
    for (int m = 0; m < 32; ++m) {
        float pm = fmaxf(p1[m], 0.0f);
        s0 += pm * Wp2[m * 4 + 0];
        s1 += pm * Wp2[m * 4 + 1];
        s2 += pm * Wp2[m * 4 + 2];
        s3 += pm * Wp2[m * 4 + 3];
    }
    float4 ov; ov.x = s0; ov.y = s1; ov.z = s2; ov.w = s3;
    *reinterpret_cast<float4*>(out + (size_t)i * 4) = ov;
}

// ---------------------------------------------------------------------------
// K6: audit — NaN -> 2^38 beacon; dead (max|gpre|<1e-8) -> 2^36. Else silent.
// ---------------------------------------------------------------------------
__global__ __launch_bounds__(256) void audit(
    const float* __restrict__ ws, float* __restrict__ out)
{
    __shared__ float red[256];
    const int t = threadIdx.x;
    float mx = 0.0f;
    for (int i = t; i < NROWS * 4; i += 256) {
        float v = ws[WS_GPRE + i];
        if (v != v) mx = 1e30f;
        else mx = fmaxf(mx, fabsf(v));
    }
    red[t] = mx;
    __syncthreads();
    for (int s = 128; s > 0; s >>= 1) {
        if (t < s) red[t] = fmaxf(red[t], red[t + s]);
        __syncthreads();
    }
    const float g = red[0];
    float V = 0.0f;
    if (g >= 1e29f)      V = ldexpf(1.0f, 38);
    else if (g <= 1e-8f) V = ldexpf(1.0f, 36);
    if (V != 0.0f) {
        for (int i = t; i < NROWS * 4; i += 256) out[i] = V;
    }
}

// ---------------------------------------------------------------------------
extern "C" void kernel_launch(void* const* d_in, const int* in_sizes, int n_in,
                              void* d_out, int out_size, void* d_ws, size_t ws_size,
                              hipStream_t stream) {
    float* out = (float*)d_out;
    float* ws  = (float*)d_ws;

    static const int dict_sizes[19] = {32768, 512, 64, 4096, 64, 4096, 64,
                                       1, 3, 1, 3, 1, 256, 64, 1, 2048, 32, 128, 4};
    if (n_in != 19) {
        beacon<<<64, 256, 0, stream>>>(out, ldexpf(1.0f + (float)n_in / 256.0f, 40));
        return;
    }
    bool is_dict = true;
    for (int i = 0; i < 19; ++i) if (in_sizes[i] != dict_sizes[i]) is_dict = false;
    if (!is_dict) {
        beacon<<<64, 256, 0, stream>>>(out, ldexpf(1.0f, 42));
        return;
    }
    if (out_size != NROWS * 4) {
        beacon<<<64, 256, 0, stream>>>(out, ldexpf(1.0f, 44));
        return;
    }
    if (ws_size < (size_t)WS_NEED * sizeof(float)) {
        beacon<<<64, 256, 0, stream>>>(out, ldexpf(1.0f, 46));
        return;
    }

    const float* in   = (const float*)d_in[0];
    const float* We   = (const float*)d_in[1];
    const float* be   = (const float*)d_in[2];
    const float* Wq   = (const float*)d_in[3];
    const float* bq   = (const float*)d_in[4];
    const float* Wk   = (const float*)d_in[5];
    const float* bk   = (const float*)d_in[6];
    const float* pa   = (const float*)d_in[7];
    const float* c1k  = (const float*)d_in[8];
    const float* c1b  = (const float*)d_in[9];
    const float* c2k  = (const float*)d_in[10];
    const float* c2b  = (const float*)d_in[11];
    const float* Wg   = (const float*)d_in[12];
    const float* bg   = (const float*)d_in[13];
    const float* ga   = (const float*)d_in[14];
    const float* Wp1  = (const float*)d_in[15];
    const float* bp1  = (const float*)d_in[16];
    const float* Wp2  = (const float*)d_in[17];
    const float* bp2  = (const float*)d_in[18];

    zero_rs<<<80, 256, 0, stream>>>(ws);
    embed_x<<<1024, 256, 0, stream>>>(in, We, be, ws);
    qk_proj<<<1024, 256, 0, stream>>>(Wq, bq, Wk, bk, ws);

    dim3 gt(64, 64);
    scores_tile<<<gt, 256, 0, stream>>>(ws);
    fused_stencil10<<<gt, 256, 0, stream>>>(c1k, c1b, c2k, c2b, pa, ws);

    dim3 ga2(16, 64);
    adj_me<<<ga2, 256, 0, stream>>>(in, ws);
    head<<<16, 256, 0, stream>>>(ws, Wg, bg, ga, Wp1, bp1, Wp2, bp2, out);
    audit<<<1, 256, 0, stream>>>(ws, out);
}

// Round 11
// 583.418 us; speedup vs baseline: 1.2393x; 1.0010x over previous
//
#include <hip/hip_runtime.h>
#include <math.h>

#define NROWS 4096

// ws float offsets
#define WS_Q    0u          // 4096*64 q
#define WS_K    262144u     // 4096*64 k
#define WS_RS   524288u     // 4096 row sums
#define WS_GPRE 528384u     // 4096*4
#define WS_X    544768u     // 4096*64 embedded x
#define BUFME   1048576u    // 4096*4096 masked*normalized scores (output of stencil)
#define BUFE    17825792u   // 4096*4096 unnormalized exp scores E
#define WS_NEED 34603008u   // floats = 138.4 MB (fits; proven in R7-R9)

static __device__ __forceinline__ float preluf(float x, float a) {
    return x > 0.0f ? x : a * x;
}

// ---------------------------------------------------------------------------
__global__ __launch_bounds__(256) void beacon(float* __restrict__ out, float v) {
    int i = blockIdx.x * 256 + threadIdx.x;
    if (i < NROWS * 4) out[i] = v;
}

// K0: zero RS + GPRE (contiguous 20480 floats)
__global__ __launch_bounds__(256) void zero_rs(float* __restrict__ ws) {
    int i = blockIdx.x * 256 + threadIdx.x;
    if (i < 20480) ws[WS_RS + i] = 0.0f;
}

// ---------------------------------------------------------------------------
// K1a: x = in@We + be   (4096x8 @ 8x64) ; thread = (row, h)
// ---------------------------------------------------------------------------
__global__ __launch_bounds__(256) void embed_x(
    const float* __restrict__ in, const float* __restrict__ We,
    const float* __restrict__ be, float* __restrict__ ws)
{
    int gid = blockIdx.x * 256 + threadIdx.x;   // 262144 total
    int i = gid >> 6, h = gid & 63;
    float s = be[h];
    #pragma unroll
    for (int d = 0; d < 8; ++d) s += in[(size_t)i * 8 + d] * We[d * 64 + h];
    ws[WS_X + gid] = s;
}

// ---------------------------------------------------------------------------
// K1b: q = x@Wq+bq ; k = x@Wk+bk  (64x64 each); thread = (row, h)
// ---------------------------------------------------------------------------
__global__ __launch_bounds__(256) void qk_proj(
    const float* __restrict__ Wq, const float* __restrict__ bq,
    const float* __restrict__ Wk, const float* __restrict__ bk,
    float* __restrict__ ws)
{
    int gid = blockIdx.x * 256 + threadIdx.x;
    int i = gid >> 6, h = gid & 63;
    const float* x = ws + WS_X + (size_t)i * 64;
    float sq = bq[h], sk = bk[h];
    for (int d = 0; d < 64; ++d) {
        float xv = x[d];
        sq += xv * Wq[d * 64 + h];
        sk += xv * Wk[d * 64 + h];
    }
    ws[WS_Q + gid] = sq;
    ws[WS_K + gid] = sk;
}

// ---------------------------------------------------------------------------
// K2: 64x64 tiles: E = exp(q.k/8) -> BUFE (unnormalized), rowsum atomics.
// ---------------------------------------------------------------------------
__global__ __launch_bounds__(256) void scores_tile(float* __restrict__ ws)
{
    __shared__ float qs[64][65];
    __shared__ float ks[64][65];
    const int br = blockIdx.y * 64, bc = blockIdx.x * 64;
    const int t = threadIdx.x;
    for (int idx = t; idx < 4096; idx += 256) {
        int r = idx >> 6, d = idx & 63;
        qs[r][d] = ws[WS_Q + (size_t)(br + r) * 64 + d];
        ks[r][d] = ws[WS_K + (size_t)(bc + r) * 64 + d];
    }
    __syncthreads();
    const int rg = t >> 6, j = t & 63;
    #pragma unroll 1
    for (int rr = 0; rr < 16; ++rr) {
        const int r = rg * 16 + rr;
        float d = 0.0f;
        #pragma unroll
        for (int dd = 0; dd < 64; ++dd) d += qs[r][dd] * ks[j][dd];
        float e = expf(d * 0.125f);
        ws[BUFE + (size_t)(br + r) * NROWS + bc + j] = e;
        float red = e;
        #pragma unroll
        for (int off = 1; off < 64; off <<= 1) red += __shfl_xor(red, off);
        if (j == 0) atomicAdd(&ws[WS_RS + br + r], red);
    }
}

// ---------------------------------------------------------------------------
// K3: fused 10-iteration stencil per 64x64 tile (halo 10).
// Loads E*il (84x84 halo, zero outside matrix) into LDS, stashes core scores
// in registers, runs 10 ping-pong iterations over the fixed [1,82]^2 region,
// then writes ME = (sigmoid(cf)>0.5) ? score : 0 for the 64x64 core.
// Exactness: after iter t, cells with buffer-margin >= t are exact; garbage
// (incl. uninitialized buf[1] ring) reaches margin-10 core only at t=11.
// ---------------------------------------------------------------------------
__global__ __launch_bounds__(256) void fused_stencil10(
    const float* __restrict__ c1k, const float* __restrict__ c1b,
    const float* __restrict__ c2k, const float* __restrict__ c2b,
    const float* __restrict__ pa, float* __restrict__ ws)
{
    const int r0 = blockIdx.y * 64, c0 = blockIdx.x * 64;
    const int t = threadIdx.x;
    __shared__ float buf[2][84][85];
    __shared__ float il_s[84];

    for (int e = t; e < 84; e += 256) {
        int gr = r0 - 10 + e;
        il_s[e] = ((unsigned)gr < (unsigned)NROWS) ? 1.0f / ws[WS_RS + gr] : 0.0f;
    }
    __syncthreads();

    for (int e = t; e < 84 * 84; e += 256) {
        int ri = e / 84, ci = e - ri * 84;
        int gr = r0 - 10 + ri, gc = c0 - 10 + ci;
        float v = 0.0f;
        if ((unsigned)gr < (unsigned)NROWS && (unsigned)gc < (unsigned)NROWS)
            v = ws[BUFE + (size_t)gr * NROWS + gc] * il_s[ri];
        buf[0][ri][ci] = v;
    }
    __syncthreads();

    // stash normalized core scores (16 cells/thread, static indexing)
    float sc[16];
    #pragma unroll
    for (int k2 = 0; k2 < 16; ++k2) {
        int e = k2 * 256 + t;
        int r = e >> 6, c = e & 63;
        sc[k2] = buf[0][10 + r][10 + c];
    }

    const float k10 = c1k[0], k11 = c1k[1], k12 = c1k[2], b1 = c1b[0];
    const float k20 = c2k[0], k21 = c2k[1], k22 = c2k[2], b2 = c2b[0];
    const float a = pa[0];

    int cur = 0;
    for (int it = 0; it < 10; ++it) {
        int nxt = cur ^ 1;
        for (int e = t; e < 82 * 82; e += 256) {
            int ri = 1 + e / 82;
            int ci = 1 + (e - (e / 82) * 82);
            float c_ = buf[cur][ri][ci];
            float lf = buf[cur][ri][ci - 1];
            float rt = buf[cur][ri][ci + 1];
            float up = buf[cur][ri - 1][ci];
            float dn = buf[cur][ri + 1][ci];
            float s = preluf(k10 * lf + k11 * c_ + k12 * rt + b1 +
                             k20 * up + k21 * c_ + k22 * dn + b2, a);
            int gr = r0 - 10 + ri, gc = c0 - 10 + ci;
            bool inm = ((unsigned)gr < (unsigned)NROWS) && ((unsigned)gc < (unsigned)NROWS);
            buf[nxt][ri][ci] = inm ? s : 0.0f;
        }
        __syncthreads();
        cur = nxt;
    }

    #pragma unroll
    for (int k2 = 0; k2 < 16; ++k2) {
        int e = k2 * 256 + t;
        int r = e >> 6, c = e & 63;
        float cf = buf[cur][10 + r][10 + c];
        float ex = expf(-cf);
        float sg = 1.0f / (1.0f + ex);
        float me = (sg > 0.5f) ? sc[k2] : 0.0f;
        ws[BUFME + (size_t)(r0 + r) * NROWS + (c0 + c)] = me;
    }
}

// ---------------------------------------------------------------------------
// K4: gpre[i][c] = sum_j ME[i][j] * o[j][c] — pure streaming reduction.
// grid (16 col-chunks x 64 row-blocks); block: 64 rows x 256 cols.
// ---------------------------------------------------------------------------
__global__ __launch_bounds__(256) void adj_me(
    const float* __restrict__ in, float* __restrict__ ws)
{
    const int br = blockIdx.y * 64;
    const int jb = blockIdx.x * 256;
    const int t = threadIdx.x;
    __shared__ float os[64][5];
    const int rg = t >> 6, j = t & 63;

    float a0[16], a1[16], a2[16], a3[16];
    #pragma unroll
    for (int rr = 0; rr < 16; ++rr) { a0[rr]=0.f; a1[rr]=0.f; a2[rr]=0.f; a3[rr]=0.f; }

    for (int ch = 0; ch < 4; ++ch) {
        const int c0 = jb + ch * 64;
        __syncthreads();
        { int jj = t >> 2, c = t & 3; os[jj][c] = in[(size_t)(c0 + jj) * 8 + c]; }
        __syncthreads();
        const int rbase = br + rg * 16;
        #pragma unroll
        for (int rr = 0; rr < 16; ++rr) {
            float me = ws[BUFME + (size_t)(rbase + rr) * NROWS + c0 + j];
            a0[rr] += me * os[j][0];
            a1[rr] += me * os[j][1];
            a2[rr] += me * os[j][2];
            a3[rr] += me * os[j][3];
        }
    }
    #pragma unroll
    for (int rr = 0; rr < 16; ++rr) {
        float v0 = a0[rr], v1 = a1[rr], v2 = a2[rr], v3 = a3[rr];
        #pragma unroll
        for (int off = 1; off < 64; off <<= 1) {
            v0 += __shfl_xor(v0, off);
            v1 += __shfl_xor(v1, off);
            v2 += __shfl_xor(v2, off);
            v3 += __shfl_xor(v3, off);
        }
        if (j == 0) {
            const int row = br + rg * 16 + rr;
            atomicAdd(&ws[WS_GPRE + (size_t)row * 4 + 0], v0);
            atomicAdd(&ws[WS_GPRE + (size_t)row * 4 + 1], v1);
            atomicAdd(&ws[WS_GPRE + (size_t)row * 4 + 2], v2);
            atomicAdd(&ws[WS_GPRE + (size_t)row * 4 + 3], v3);
        }
    }
}

// ---------------------------------------------------------------------------
// K5: head — g = prelu(gpre@Wg(4x64)+bg); pred = relu(g@Wp1(64x32)+bp1)@Wp2+bp2
// ---------------------------------------------------------------------------
__global__ __launch_bounds__(256) void head(
    const float* __restrict__ ws,
    const float* __restrict__ Wg, const float* __restrict__ bg, const float* __restrict__ ga,
    const float* __restrict__ Wp1, const float* __restrict__ bp1,
    const float* __restrict__ Wp2, const float* __restrict__ bp2,
    float* __restrict__ out)
{
    int i = blockIdx.x * 256 + threadIdx.x;
    if (i >= NROWS) return;
    const float a = ga[0];
    float gp[4];
    #pragma unroll
    for (int c = 0; c < 4; ++c) gp[c] = ws[WS_GPRE + (size_t)i * 4 + c];
    float p1[32];
    #pragma unroll
    for (int m = 0; m < 32; ++m) p1[m] = bp1[m];
    for (int h = 0; h < 64; ++h) {
        float s = bg[h];
        #pragma unroll
        for (int c = 0; c < 4; ++c) s += gp[c] * Wg[c * 64 + h];
        float gh = preluf(s, a);
        #pragma unroll
        for (int m = 0; m < 32; ++m) p1[m] += gh * Wp1[h * 32 + m];
    }
    float s0 = bp2[0], s1 = bp2[1], s2 = bp2[2], s3 = bp2[3];
    #pragma unroll
    for (int m = 0; m < 32; ++m) {
        float pm = fmaxf(p1[m], 0.0f);
        s0 += pm * Wp2[m * 4 + 0];
        s1 += pm * Wp2[m * 4 + 1];
        s2 += pm * Wp2[m * 4 + 2];
        s3 += pm * Wp2[m * 4 + 3];
    }
    float4 ov; ov.x = s0; ov.y = s1; ov.z = s2; ov.w = s3;
    *reinterpret_cast<float4*>(out + (size_t)i * 4) = ov;
}

// ---------------------------------------------------------------------------
// K6: audit — NaN -> 2^38 beacon; dead (max|gpre|<1e-8) -> 2^36. Else silent.
// ---------------------------------------------------------------------------
__global__ __launch_bounds__(256) void audit(
    const float* __restrict__ ws, float* __restrict__ out)
{
    __shared__ float red[256];
    const int t = threadIdx.x;
    float mx = 0.0f;
    for (int i = t; i < NROWS * 4; i += 256) {
        float v = ws[WS_GPRE + i];
        if (v != v) mx = 1e30f;
        else mx = fmaxf(mx, fabsf(v));
    }
    red[t] = mx;
    __syncthreads();
    for (int s = 128; s > 0; s >>= 1) {
        if (t < s) red[t] = fmaxf(red[t], red[t + s]);
        __syncthreads();
    }
    const float g = red[0];
    float V = 0.0f;
    if (g >= 1e29f)      V = ldexpf(1.0f, 38);
    else if (g <= 1e-8f) V = ldexpf(1.0f, 36);
    if (V != 0.0f) {
        for (int i = t; i < NROWS * 4; i += 256) out[i] = V;
    }
}

// ---------------------------------------------------------------------------
extern "C" void kernel_launch(void* const* d_in, const int* in_sizes, int n_in,
                              void* d_out, int out_size, void* d_ws, size_t ws_size,
                              hipStream_t stream) {
    float* out = (float*)d_out;
    float* ws  = (float*)d_ws;

    static const int dict_sizes[19] = {32768, 512, 64, 4096, 64, 4096, 64,
                                       1, 3, 1, 3, 1, 256, 64, 1, 2048, 32, 128, 4};
    if (n_in != 19) {
        beacon<<<64, 256, 0, stream>>>(out, ldexpf(1.0f + (float)n_in / 256.0f, 40));
        return;
    }
    bool is_dict = true;
    for (int i = 0; i < 19; ++i) if (in_sizes[i] != dict_sizes[i]) is_dict = false;
    if (!is_dict) {
        beacon<<<64, 256, 0, stream>>>(out, ldexpf(1.0f, 42));
        return;
    }
    if (out_size != NROWS * 4) {
        beacon<<<64, 256, 0, stream>>>(out, ldexpf(1.0f, 44));
        return;
    }
    if (ws_size < (size_t)WS_NEED * sizeof(float)) {
        beacon<<<64, 256, 0, stream>>>(out, ldexpf(1.0f, 46));
        return;
    }

    const float* in   = (const float*)d_in[0];
    const float* We   = (const float*)d_in[1];
    const float* be   = (const float*)d_in[2];
    const float* Wq   = (const float*)d_in[3];
    const float* bq   = (const float*)d_in[4];
    const float* Wk   = (const float*)d_in[5];
    const float* bk   = (const float*)d_in[6];
    const float* pa   = (const float*)d_in[7];
    const float* c1k  = (const float*)d_in[8];
    const float* c1b  = (const float*)d_in[9];
    const float* c2k  = (const float*)d_in[10];
    const float* c2b  = (const float*)d_in[11];
    const float* Wg   = (const float*)d_in[12];
    const float* bg   = (const float*)d_in[13];
    const float* ga   = (const float*)d_in[14];
    const float* Wp1  = (const float*)d_in[15];
    const float* bp1  = (const float*)d_in[16];
    const float* Wp2  = (const float*)d_in[17];
    const float* bp2  = (const float*)d_in[18];

    zero_rs<<<80, 256, 0, stream>>>(ws);
    embed_x<<<1024, 256, 0, stream>>>(in, We, be, ws);
    qk_proj<<<1024, 256, 0, stream>>>(Wq, bq, Wk, bk, ws);

    dim3 gt(64, 64);
    scores_tile<<<gt, 256, 0, stream>>>(ws);
    fused_stencil10<<<gt, 256, 0, stream>>>(c1k, c1b, c2k, c2b, pa, ws);

    dim3 ga2(16, 64);
    adj_me<<<ga2, 256, 0, stream>>>(in, ws);
    head<<<16, 256, 0, stream>>>(ws, Wg, bg, ga, Wp1, bp1, Wp2, bp2, out);
    audit<<<1, 256, 0, stream>>>(ws, out);
}

// Round 12
// 530.665 us; speedup vs baseline: 1.3625x; 1.0994x over previous
//
#include <hip/hip_runtime.h>
#include <math.h>

#define NROWS 4096

// ws float offsets
#define WS_Q    0u          // 4096*64 q
#define WS_K    262144u     // 4096*64 k
#define WS_RS   524288u     // 4096 row sums
#define WS_GPRE 528384u     // 4096*4
#define WS_X    544768u     // 4096*64 embedded x
#define BUFME   1048576u    // 4096*4096 masked*normalized scores
#define BUFE    17825792u   // 4096*4096 unnormalized exp scores E
#define WS_NEED 34603008u   // floats = 138.4 MB

static __device__ __forceinline__ float preluf(float x, float a) {
    return x > 0.0f ? x : a * x;
}

// ---------------------------------------------------------------------------
__global__ __launch_bounds__(256) void beacon(float* __restrict__ out, float v) {
    int i = blockIdx.x * 256 + threadIdx.x;
    if (i < NROWS * 4) out[i] = v;
}

__global__ __launch_bounds__(256) void zero_rs(float* __restrict__ ws) {
    int i = blockIdx.x * 256 + threadIdx.x;
    if (i < 20480) ws[WS_RS + i] = 0.0f;
}

// ---------------------------------------------------------------------------
__global__ __launch_bounds__(256) void embed_x(
    const float* __restrict__ in, const float* __restrict__ We,
    const float* __restrict__ be, float* __restrict__ ws)
{
    int gid = blockIdx.x * 256 + threadIdx.x;
    int i = gid >> 6, h = gid & 63;
    float s = be[h];
    #pragma unroll
    for (int d = 0; d < 8; ++d) s += in[(size_t)i * 8 + d] * We[d * 64 + h];
    ws[WS_X + gid] = s;
}

__global__ __launch_bounds__(256) void qk_proj(
    const float* __restrict__ Wq, const float* __restrict__ bq,
    const float* __restrict__ Wk, const float* __restrict__ bk,
    float* __restrict__ ws)
{
    int gid = blockIdx.x * 256 + threadIdx.x;
    int i = gid >> 6, h = gid & 63;
    const float* x = ws + WS_X + (size_t)i * 64;
    float sq = bq[h], sk = bk[h];
    for (int d = 0; d < 64; ++d) {
        float xv = x[d];
        sq += xv * Wq[d * 64 + h];
        sk += xv * Wk[d * 64 + h];
    }
    ws[WS_Q + gid] = sq;
    ws[WS_K + gid] = sk;
}

// ---------------------------------------------------------------------------
__global__ __launch_bounds__(256) void scores_tile(float* __restrict__ ws)
{
    __shared__ float qs[64][65];
    __shared__ float ks[64][65];
    const int br = blockIdx.y * 64, bc = blockIdx.x * 64;
    const int t = threadIdx.x;
    for (int idx = t; idx < 4096; idx += 256) {
        int r = idx >> 6, d = idx & 63;
        qs[r][d] = ws[WS_Q + (size_t)(br + r) * 64 + d];
        ks[r][d] = ws[WS_K + (size_t)(bc + r) * 64 + d];
    }
    __syncthreads();
    const int rg = t >> 6, j = t & 63;
    #pragma unroll 1
    for (int rr = 0; rr < 16; ++rr) {
        const int r = rg * 16 + rr;
        float d = 0.0f;
        #pragma unroll
        for (int dd = 0; dd < 64; ++dd) d += qs[r][dd] * ks[j][dd];
        float e = expf(d * 0.125f);
        ws[BUFE + (size_t)(br + r) * NROWS + bc + j] = e;
        float red = e;
        #pragma unroll
        for (int off = 1; off < 64; off <<= 1) red += __shfl_xor(red, off);
        if (j == 0) atomicAdd(&ws[WS_RS + br + r], red);
    }
}

// ---------------------------------------------------------------------------
// K3: fused 10-iteration stencil per 64x64 tile (halo 10).
// Interior blocks: register-rolling row sweep, 21 col-quads x 12 row-bands,
// iteration-t rows clamped to the needed cone [t, 83-t]. Pad-column garbage
// front advances 1 col/iter, always 1 column outside the needed set.
// Edge blocks (~6%): scalar path with out-of-matrix zero forcing.
// ---------------------------------------------------------------------------
__global__ __launch_bounds__(256) void fused_stencil10(
    const float* __restrict__ c1k, const float* __restrict__ c1b,
    const float* __restrict__ c2k, const float* __restrict__ c2b,
    const float* __restrict__ pa, float* __restrict__ ws)
{
    const int bx = blockIdx.x, by = blockIdx.y;
    const int r0 = by * 64, c0t = bx * 64;
    const int t = threadIdx.x;
    __shared__ float buf[2][84][85];
    __shared__ float il_s[84];

    for (int e = t; e < 84; e += 256) {
        int gr = r0 - 10 + e;
        il_s[e] = ((unsigned)gr < (unsigned)NROWS) ? 1.0f / ws[WS_RS + gr] : 0.0f;
    }
    __syncthreads();

    for (int e = t; e < 84 * 84; e += 256) {
        int ri = e / 84, ci = e - ri * 84;
        int gr = r0 - 10 + ri, gc = c0t - 10 + ci;
        float v = 0.0f;
        if ((unsigned)gr < (unsigned)NROWS && (unsigned)gc < (unsigned)NROWS)
            v = ws[BUFE + (size_t)gr * NROWS + gc] * il_s[ri];
        buf[0][ri][ci] = v;
    }
    __syncthreads();

    // stash normalized core scores (static indexing)
    float sc[16];
    #pragma unroll
    for (int k2 = 0; k2 < 16; ++k2) {
        int e = k2 * 256 + t;
        sc[k2] = buf[0][10 + (e >> 6)][10 + (e & 63)];
    }

    const float k10 = c1k[0], k11 = c1k[1], k12 = c1k[2];
    const float k20 = c2k[0], k21 = c2k[1], k22 = c2k[2];
    const float bb = c1b[0] + c2b[0];
    const float a = pa[0];

    const bool edge = (bx == 0) || (bx == 63) || (by == 0) || (by == 63);
    int cur = 0;

    if (!edge) {
        const int cq = t % 21;            // col-quad 0..20
        const int rg = t / 21;            // row-band 0..11 (t<252)
        const int c0 = 1 + 4 * cq;        // cols c0..c0+3
        const int rlo0 = 1 + 7 * rg;
        const int rhi0 = (7 + 7 * rg) > 82 ? 82 : (7 + 7 * rg);
        const bool act = (t < 252);
        for (int it = 1; it <= 10; ++it) {
            const int nxt = cur ^ 1;
            if (act) {
                const int rlo = rlo0 > it ? rlo0 : it;
                const int rhi = rhi0 < (83 - it) ? rhi0 : (83 - it);
                if (rlo <= rhi) {
                    float u0 = buf[cur][rlo - 1][c0 + 0];
                    float u1 = buf[cur][rlo - 1][c0 + 1];
                    float u2 = buf[cur][rlo - 1][c0 + 2];
                    float u3 = buf[cur][rlo - 1][c0 + 3];
                    float e0 = buf[cur][rlo][c0 - 1];
                    float e1 = buf[cur][rlo][c0 + 0];
                    float e2 = buf[cur][rlo][c0 + 1];
                    float e3 = buf[cur][rlo][c0 + 2];
                    float e4 = buf[cur][rlo][c0 + 3];
                    float e5 = buf[cur][rlo][c0 + 4];
                    for (int r = rlo; r <= rhi; ++r) {
                        float d0 = buf[cur][r + 1][c0 - 1];
                        float d1 = buf[cur][r + 1][c0 + 0];
                        float d2 = buf[cur][r + 1][c0 + 1];
                        float d3 = buf[cur][r + 1][c0 + 2];
                        float d4 = buf[cur][r + 1][c0 + 3];
                        float d5 = buf[cur][r + 1][c0 + 4];
                        float s0 = k10 * e0 + k11 * e1 + k12 * e2 + bb + k20 * u0 + k21 * e1 + k22 * d1;
                        float s1 = k10 * e1 + k11 * e2 + k12 * e3 + bb + k20 * u1 + k21 * e2 + k22 * d2;
                        float s2 = k10 * e2 + k11 * e3 + k12 * e4 + bb + k20 * u2 + k21 * e3 + k22 * d3;
                        float s3 = k10 * e3 + k11 * e4 + k12 * e5 + bb + k20 * u3 + k21 * e4 + k22 * d4;
                        buf[nxt][r][c0 + 0] = preluf(s0, a);
                        buf[nxt][r][c0 + 1] = preluf(s1, a);
                        buf[nxt][r][c0 + 2] = preluf(s2, a);
                        buf[nxt][r][c0 + 3] = preluf(s3, a);
                        u0 = e1; u1 = e2; u2 = e3; u3 = e4;
                        e0 = d0; e1 = d1; e2 = d2; e3 = d3; e4 = d4; e5 = d5;
                    }
                }
            }
            __syncthreads();
            cur = nxt;
        }
    } else {
        for (int it = 1; it <= 10; ++it) {
            const int nxt = cur ^ 1;
            for (int e = t; e < 82 * 82; e += 256) {
                int ri = 1 + e / 82;
                int ci = 1 + (e - (e / 82) * 82);
                float c_ = buf[cur][ri][ci];
                float lf = buf[cur][ri][ci - 1];
                float rt = buf[cur][ri][ci + 1];
                float up = buf[cur][ri - 1][ci];
                float dn = buf[cur][ri + 1][ci];
                float s = preluf(k10 * lf + k11 * c_ + k12 * rt + bb +
                                 k20 * up + k21 * c_ + k22 * dn, a);
                int gr = r0 - 10 + ri, gc = c0t - 10 + ci;
                bool inm = ((unsigned)gr < (unsigned)NROWS) && ((unsigned)gc < (unsigned)NROWS);
                buf[nxt][ri][ci] = inm ? s : 0.0f;
            }
            __syncthreads();
            cur = nxt;
        }
    }

    #pragma unroll
    for (int k2 = 0; k2 < 16; ++k2) {
        int e = k2 * 256 + t;
        int r = e >> 6, c = e & 63;
        float cf = buf[cur][10 + r][10 + c];
        float ex = expf(-cf);
        float sg = 1.0f / (1.0f + ex);
        float me = (sg > 0.5f) ? sc[k2] : 0.0f;
        ws[BUFME + (size_t)(r0 + r) * NROWS + (c0t + c)] = me;
    }
}

// ---------------------------------------------------------------------------
// K4: gpre[i][c] = sum_j ME[i][j] * o[j][c] — streaming reduction.
// ---------------------------------------------------------------------------
__global__ __launch_bounds__(256) void adj_me(
    const float* __restrict__ in, float* __restrict__ ws)
{
    const int br = blockIdx.y * 64;
    const int jb = blockIdx.x * 256;
    const int t = threadIdx.x;
    __shared__ float os[64][5];
    const int rg = t >> 6, j = t & 63;

    float a0[16], a1[16], a2[16], a3[16];
    #pragma unroll
    for (int rr = 0; rr < 16; ++rr) { a0[rr]=0.f; a1[rr]=0.f; a2[rr]=0.f; a3[rr]=0.f; }

    for (int ch = 0; ch < 4; ++ch) {
        const int c0 = jb + ch * 64;
        __syncthreads();
        { int jj = t >> 2, c = t & 3; os[jj][c] = in[(size_t)(c0 + jj) * 8 + c]; }
        __syncthreads();
        const int rbase = br + rg * 16;
        #pragma unroll
        for (int rr = 0; rr < 16; ++rr) {
            float me = ws[BUFME + (size_t)(rbase + rr) * NROWS + c0 + j];
            a0[rr] += me * os[j][0];
            a1[rr] += me * os[j][1];
            a2[rr] += me * os[j][2];
            a3[rr] += me * os[j][3];
        }
    }
    #pragma unroll
    for (int rr = 0; rr < 16; ++rr) {
        float v0 = a0[rr], v1 = a1[rr], v2 = a2[rr], v3 = a3[rr];
        #pragma unroll
        for (int off = 1; off < 64; off <<= 1) {
            v0 += __shfl_xor(v0, off);
            v1 += __shfl_xor(v1, off);
            v2 += __shfl_xor(v2, off);
            v3 += __shfl_xor(v3, off);
        }
        if (j == 0) {
            const int row = br + rg * 16 + rr;
            atomicAdd(&ws[WS_GPRE + (size_t)row * 4 + 0], v0);
            atomicAdd(&ws[WS_GPRE + (size_t)row * 4 + 1], v1);
            atomicAdd(&ws[WS_GPRE + (size_t)row * 4 + 2], v2);
            atomicAdd(&ws[WS_GPRE + (size_t)row * 4 + 3], v3);
        }
    }
}

// ---------------------------------------------------------------------------
__global__ __launch_bounds__(256) void head(
    const float* __restrict__ ws,
    const float* __restrict__ Wg, const float* __restrict__ bg, const float* __restrict__ ga,
    const float* __restrict__ Wp1, const float* __restrict__ bp1,
    const float* __restrict__ Wp2, const float* __restrict__ bp2,
    float* __restrict__ out)
{
    int i = blockIdx.x * 256 + threadIdx.x;
    if (i >= NROWS) return;
    const float a = ga[0];
    float gp[4];
    #pragma unroll
    for (int c = 0; c < 4; ++c) gp[c] = ws[WS_GPRE + (size_t)i * 4 + c];
    float p1[32];
    #pragma unroll
    for (int m = 0; m < 32; ++m) p1[m] = bp1[m];
    for (int h = 0; h < 64; ++h) {
        float s = bg[h];
        #pragma unroll
        for (int c = 0; c < 4; ++c) s += gp[c] * Wg[c * 64 + h];
        float gh = preluf(s, a);
        #pragma unroll
        for (int m = 0; m < 32; ++m) p1[m] += gh * Wp1[h * 32 + m];
    }
    float s0 = bp2[0], s1 = bp2[1], s2 = bp2[2], s3 = bp2[3];
    #pragma unroll
    for (int m = 0; m < 32; ++m) {
        float pm = fmaxf(p1[m], 0.0f);
        s0 += pm * Wp2[m * 4 + 0];
        s1 += pm * Wp2[m * 4 + 1];
        s2 += pm * Wp2[m * 4 + 2];
        s3 += pm * Wp2[m * 4 + 3];
    }
    float4 ov; ov.x = s0; ov.y = s1; ov.z = s2; ov.w = s3;
    *reinterpret_cast<float4*>(out + (size_t)i * 4) = ov;
}

// ---------------------------------------------------------------------------
__global__ __launch_bounds__(256) void audit(
    const float* __restrict__ ws, float* __restrict__ out)
{
    __shared__ float red[256];
    const int t = threadIdx.x;
    float mx = 0.0f;
    for (int i = t; i < NROWS * 4; i += 256) {
        float v = ws[WS_GPRE + i];
        if (v != v) mx = 1e30f;
        else mx = fmaxf(mx, fabsf(v));
    }
    red[t] = mx;
    __syncthreads();
    for (int s = 128; s > 0; s >>= 1) {
        if (t < s) red[t] = fmaxf(red[t], red[t + s]);
        __syncthreads();
    }
    const float g = red[0];
    float V = 0.0f;
    if (g >= 1e29f)      V = ldexpf(1.0f, 38);
    else if (g <= 1e-8f) V = ldexpf(1.0f, 36);
    if (V != 0.0f) {
        for (int i = t; i < NROWS * 4; i += 256) out[i] = V;
    }
}

// ---------------------------------------------------------------------------
extern "C" void kernel_launch(void* const* d_in, const int* in_sizes, int n_in,
                              void* d_out, int out_size, void* d_ws, size_t ws_size,
                              hipStream_t stream) {
    float* out = (float*)d_out;
    float* ws  = (float*)d_ws;

    static const int dict_sizes[19] = {32768, 512, 64, 4096, 64, 4096, 64,
                                       1, 3, 1, 3, 1, 256, 64, 1, 2048, 32, 128, 4};
    if (n_in != 19) {
        beacon<<<64, 256, 0, stream>>>(out, ldexpf(1.0f + (float)n_in / 256.0f, 40));
        return;
    }
    bool is_dict = true;
    for (int i = 0; i < 19; ++i) if (in_sizes[i] != dict_sizes[i]) is_dict = false;
    if (!is_dict) {
        beacon<<<64, 256, 0, stream>>>(out, ldexpf(1.0f, 42));
        return;
    }
    if (out_size != NROWS * 4) {
        beacon<<<64, 256, 0, stream>>>(out, ldexpf(1.0f, 44));
        return;
    }
    if (ws_size < (size_t)WS_NEED * sizeof(float)) {
        beacon<<<64, 256, 0, stream>>>(out, ldexpf(1.0f, 46));
        return;
    }

    const float* in   = (const float*)d_in[0];
    const float* We   = (const float*)d_in[1];
    const float* be   = (const float*)d_in[2];
    const float* Wq   = (const float*)d_in[3];
    const float* bq   = (const float*)d_in[4];
    const float* Wk   = (const float*)d_in[5];
    const float* bk   = (const float*)d_in[6];
    const float* pa   = (const float*)d_in[7];
    const float* c1k  = (const float*)d_in[8];
    const float* c1b  = (const float*)d_in[9];
    const float* c2k  = (const float*)d_in[10];
    const float* c2b  = (const float*)d_in[11];
    const float* Wg   = (const float*)d_in[12];
    const float* bg   = (const float*)d_in[13];
    const float* ga   = (const float*)d_in[14];
    const float* Wp1  = (const float*)d_in[15];
    const float* bp1  = (const float*)d_in[16];
    const float* Wp2  = (const float*)d_in[17];
    const float* bp2  = (const float*)d_in[18];

    zero_rs<<<80, 256, 0, stream>>>(ws);
    embed_x<<<1024, 256, 0, stream>>>(in, We, be, ws);
    qk_proj<<<1024, 256, 0, stream>>>(Wq, bq, Wk, bk, ws);

    dim3 gt(64, 64);
    scores_tile<<<gt, 256, 0, stream>>>(ws);
    fused_stencil10<<<gt, 256, 0, stream>>>(c1k, c1b, c2k, c2b, pa, ws);

    dim3 ga2(16, 64);
    adj_me<<<ga2, 256, 0, stream>>>(in, ws);
    head<<<16, 256, 0, stream>>>(ws, Wg, bg, ga, Wp1, bp1, Wp2, bp2, out);
    audit<<<1, 256, 0, stream>>>(ws, out);
}

// Round 13
// 497.513 us; speedup vs baseline: 1.4533x; 1.0666x over previous
//
#include <hip/hip_runtime.h>
#include <math.h>

#define NROWS 4096

// ws float offsets
#define WS_Q    0u          // 4096*64 q
#define WS_K    262144u     // 4096*64 k
#define WS_RS   524288u     // 4096 row sums
#define WS_GPRE 528384u     // 4096*4
#define WS_X    544768u     // 4096*64 embedded x
#define BUFME   1048576u    // 4096*4096 masked*normalized scores
#define BUFE    17825792u   // 4096*4096 unnormalized exp scores E
#define WS_NEED 34603008u   // floats = 138.4 MB

static __device__ __forceinline__ float preluf(float x, float a) {
    return x > 0.0f ? x : a * x;
}

// ---------------------------------------------------------------------------
__global__ __launch_bounds__(256) void beacon(float* __restrict__ out, float v) {
    int i = blockIdx.x * 256 + threadIdx.x;
    if (i < NROWS * 4) out[i] = v;
}

__global__ __launch_bounds__(256) void zero_rs(float* __restrict__ ws) {
    int i = blockIdx.x * 256 + threadIdx.x;
    if (i < 20480) ws[WS_RS + i] = 0.0f;
}

// ---------------------------------------------------------------------------
__global__ __launch_bounds__(256) void embed_x(
    const float* __restrict__ in, const float* __restrict__ We,
    const float* __restrict__ be, float* __restrict__ ws)
{
    int gid = blockIdx.x * 256 + threadIdx.x;
    int i = gid >> 6, h = gid & 63;
    float s = be[h];
    #pragma unroll
    for (int d = 0; d < 8; ++d) s += in[(size_t)i * 8 + d] * We[d * 64 + h];
    ws[WS_X + gid] = s;
}

__global__ __launch_bounds__(256) void qk_proj(
    const float* __restrict__ Wq, const float* __restrict__ bq,
    const float* __restrict__ Wk, const float* __restrict__ bk,
    float* __restrict__ ws)
{
    int gid = blockIdx.x * 256 + threadIdx.x;
    int i = gid >> 6, h = gid & 63;
    const float* x = ws + WS_X + (size_t)i * 64;
    float sq = bq[h], sk = bk[h];
    for (int d = 0; d < 64; ++d) {
        float xv = x[d];
        sq += xv * Wq[d * 64 + h];
        sk += xv * Wk[d * 64 + h];
    }
    ws[WS_Q + gid] = sq;
    ws[WS_K + gid] = sk;
}

// ---------------------------------------------------------------------------
__global__ __launch_bounds__(256) void scores_tile(float* __restrict__ ws)
{
    __shared__ float qs[64][65];
    __shared__ float ks[64][65];
    const int br = blockIdx.y * 64, bc = blockIdx.x * 64;
    const int t = threadIdx.x;
    for (int idx = t; idx < 4096; idx += 256) {
        int r = idx >> 6, d = idx & 63;
        qs[r][d] = ws[WS_Q + (size_t)(br + r) * 64 + d];
        ks[r][d] = ws[WS_K + (size_t)(bc + r) * 64 + d];
    }
    __syncthreads();
    const int rg = t >> 6, j = t & 63;
    #pragma unroll 1
    for (int rr = 0; rr < 16; ++rr) {
        const int r = rg * 16 + rr;
        float d = 0.0f;
        #pragma unroll
        for (int dd = 0; dd < 64; ++dd) d += qs[r][dd] * ks[j][dd];
        float e = expf(d * 0.125f);
        ws[BUFE + (size_t)(br + r) * NROWS + bc + j] = e;
        float red = e;
        #pragma unroll
        for (int off = 1; off < 64; off <<= 1) red += __shfl_xor(red, off);
        if (j == 0) atomicAdd(&ws[WS_RS + br + r], red);
    }
}

// ---------------------------------------------------------------------------
// K3: fused 10-iteration stencil per 64x64 tile (halo 10).
// Interior blocks: column-per-thread rolling sweep. Thread = (band g in 0..2,
// col ci = 1 + t%85, active if t%85 < 82). Lanes hit consecutive LDS addrs
// (stride-1, conflict-free). Rolling regs: 3 reads + 1 write per cell.
// Rows AND cols clamped to exactness cone [it, 83-it] (exact set after iter
// t is [t,83-t]^2; core [10,73]^2 needs exactly that).
// Edge blocks (~6%): scalar path with out-of-matrix zero forcing.
// ---------------------------------------------------------------------------
__global__ __launch_bounds__(256) void fused_stencil10(
    const float* __restrict__ c1k, const float* __restrict__ c1b,
    const float* __restrict__ c2k, const float* __restrict__ c2b,
    const float* __restrict__ pa, float* __restrict__ ws)
{
    const int bx = blockIdx.x, by = blockIdx.y;
    const int r0 = by * 64, c0t = bx * 64;
    const int t = threadIdx.x;
    __shared__ float buf[2][84][85];
    __shared__ float il_s[84];

    for (int e = t; e < 84; e += 256) {
        int gr = r0 - 10 + e;
        il_s[e] = ((unsigned)gr < (unsigned)NROWS) ? 1.0f / ws[WS_RS + gr] : 0.0f;
    }
    __syncthreads();

    const bool edge = (bx == 0) || (bx == 63) || (by == 0) || (by == 63);

    // ---- halo load: fixed ci = t%84, rows t/84 + 3k (252 active threads)
    {
        const int lci = t % 84;
        const int lr0 = t / 84;          // 0..3 (t<252 -> 0..2)
        if (lr0 < 3) {
            if (!edge) {
                const size_t gbase = BUFE + (size_t)(r0 - 10) * NROWS + (c0t - 10) + lci;
                for (int ri = lr0; ri < 84; ri += 3)
                    buf[0][ri][lci] = ws[gbase + (size_t)ri * NROWS] * il_s[ri];
            } else {
                for (int ri = lr0; ri < 84; ri += 3) {
                    int gr = r0 - 10 + ri, gc = c0t - 10 + lci;
                    float v = 0.0f;
                    if ((unsigned)gr < (unsigned)NROWS && (unsigned)gc < (unsigned)NROWS)
                        v = ws[BUFE + (size_t)gr * NROWS + gc] * il_s[ri];
                    buf[0][ri][lci] = v;
                }
            }
        }
    }
    __syncthreads();

    // stash normalized core scores (static indexing, stride-1)
    float sc[16];
    #pragma unroll
    for (int k2 = 0; k2 < 16; ++k2) {
        int e = k2 * 256 + t;
        sc[k2] = buf[0][10 + (e >> 6)][10 + (e & 63)];
    }

    const float k10 = c1k[0], k11 = c1k[1], k12 = c1k[2];
    const float k20 = c2k[0], k21 = c2k[1], k22 = c2k[2];
    const float bb = c1b[0] + c2b[0];
    const float a = pa[0];

    int cur = 0;

    if (!edge) {
        const int ci = 1 + t % 85;       // 1..85 (85 -> inactive)
        const int g  = t / 85;           // 0..3 (t=255 -> g=3 inactive)
        const int blo = (g == 0) ? 1 : (g == 1) ? 29 : 56;
        const int bhi = (g == 0) ? 28 : (g == 1) ? 55 : 82;
        const bool colok = (ci <= 82) && (g < 3);
        for (int it = 1; it <= 10; ++it) {
            const int nxt = cur ^ 1;
            if (colok && ci >= it && ci <= 83 - it) {
                const int rlo = blo > it ? blo : it;
                const int rhi = bhi < (83 - it) ? bhi : (83 - it);
                if (rlo <= rhi) {
                    float u  = buf[cur][rlo - 1][ci];
                    float l  = buf[cur][rlo][ci - 1];
                    float c  = buf[cur][rlo][ci];
                    float rr = buf[cur][rlo][ci + 1];
                    for (int r = rlo; r <= rhi; ++r) {
                        float d = buf[cur][r + 1][ci];
                        float s = k10 * l + k11 * c + k12 * rr + bb +
                                  k20 * u + k21 * c + k22 * d;
                        buf[nxt][r][ci] = preluf(s, a);
                        u = c;
                        l = buf[cur][r + 1][ci - 1];
                        rr = buf[cur][r + 1][ci + 1];
                        c = d;
                    }
                }
            }
            __syncthreads();
            cur = nxt;
        }
    } else {
        for (int it = 1; it <= 10; ++it) {
            const int nxt = cur ^ 1;
            for (int e = t; e < 82 * 82; e += 256) {
                int ri = 1 + e / 82;
                int ci = 1 + (e - (e / 82) * 82);
                float c_ = buf[cur][ri][ci];
                float lf = buf[cur][ri][ci - 1];
                float rt = buf[cur][ri][ci + 1];
                float up = buf[cur][ri - 1][ci];
                float dn = buf[cur][ri + 1][ci];
                float s = preluf(k10 * lf + k11 * c_ + k12 * rt + bb +
                                 k20 * up + k21 * c_ + k22 * dn, a);
                int gr = r0 - 10 + ri, gc = c0t - 10 + ci;
                bool inm = ((unsigned)gr < (unsigned)NROWS) && ((unsigned)gc < (unsigned)NROWS);
                buf[nxt][ri][ci] = inm ? s : 0.0f;
            }
            __syncthreads();
            cur = nxt;
        }
    }

    #pragma unroll
    for (int k2 = 0; k2 < 16; ++k2) {
        int e = k2 * 256 + t;
        int r = e >> 6, c = e & 63;
        float cf = buf[cur][10 + r][10 + c];
        float ex = expf(-cf);
        float sg = 1.0f / (1.0f + ex);
        float me = (sg > 0.5f) ? sc[k2] : 0.0f;
        ws[BUFME + (size_t)(r0 + r) * NROWS + (c0t + c)] = me;
    }
}

// ---------------------------------------------------------------------------
// K4: gpre[i][c] = sum_j ME[i][j] * o[j][c] — streaming reduction.
// ---------------------------------------------------------------------------
__global__ __launch_bounds__(256) void adj_me(
    const float* __restrict__ in, float* __restrict__ ws)
{
    const int br = blockIdx.y * 64;
    const int jb = blockIdx.x * 256;
    const int t = threadIdx.x;
    __shared__ float os[64][5];
    const int rg = t >> 6, j = t & 63;

    float a0[16], a1[16], a2[16], a3[16];
    #pragma unroll
    for (int rr = 0; rr < 16; ++rr) { a0[rr]=0.f; a1[rr]=0.f; a2[rr]=0.f; a3[rr]=0.f; }

    for (int ch = 0; ch < 4; ++ch) {
        const int c0 = jb + ch * 64;
        __syncthreads();
        { int jj = t >> 2, c = t & 3; os[jj][c] = in[(size_t)(c0 + jj) * 8 + c]; }
        __syncthreads();
        const int rbase = br + rg * 16;
        #pragma unroll
        for (int rr = 0; rr < 16; ++rr) {
            float me = ws[BUFME + (size_t)(rbase + rr) * NROWS + c0 + j];
            a0[rr] += me * os[j][0];
            a1[rr] += me * os[j][1];
            a2[rr] += me * os[j][2];
            a3[rr] += me * os[j][3];
        }
    }
    #pragma unroll
    for (int rr = 0; rr < 16; ++rr) {
        float v0 = a0[rr], v1 = a1[rr], v2 = a2[rr], v3 = a3[rr];
        #pragma unroll
        for (int off = 1; off < 64; off <<= 1) {
            v0 += __shfl_xor(v0, off);
            v1 += __shfl_xor(v1, off);
            v2 += __shfl_xor(v2, off);
            v3 += __shfl_xor(v3, off);
        }
        if (j == 0) {
            const int row = br + rg * 16 + rr;
            atomicAdd(&ws[WS_GPRE + (size_t)row * 4 + 0], v0);
            atomicAdd(&ws[WS_GPRE + (size_t)row * 4 + 1], v1);
            atomicAdd(&ws[WS_GPRE + (size_t)row * 4 + 2], v2);
            atomicAdd(&ws[WS_GPRE + (size_t)row * 4 + 3], v3);
        }
    }
}

// ---------------------------------------------------------------------------
__global__ __launch_bounds__(256) void head(
    const float* __restrict__ ws,
    const float* __restrict__ Wg, const float* __restrict__ bg, const float* __restrict__ ga,
    const float* __restrict__ Wp1, const float* __restrict__ bp1,
    const float* __restrict__ Wp2, const float* __restrict__ bp2,
    float* __restrict__ out)
{
    int i = blockIdx.x * 256 + threadIdx.x;
    if (i >= NROWS) return;
    const float a = ga[0];
    float gp[4];
    #pragma unroll
    for (int c = 0; c < 4; ++c) gp[c] = ws[WS_GPRE + (size_t)i * 4 + c];
    float p1[32];
    #pragma unroll
    for (int m = 0; m < 32; ++m) p1[m] = bp1[m];
    for (int h = 0; h < 64; ++h) {
        float s = bg[h];
        #pragma unroll
        for (int c = 0; c < 4; ++c) s += gp[c] * Wg[c * 64 + h];
        float gh = preluf(s, a);
        #pragma unroll
        for (int m = 0; m < 32; ++m) p1[m] += gh * Wp1[h * 32 + m];
    }
    float s0 = bp2[0], s1 = bp2[1], s2 = bp2[2], s3 = bp2[3];
    #pragma unroll
    for (int m = 0; m < 32; ++m) {
        float pm = fmaxf(p1[m], 0.0f);
        s0 += pm * Wp2[m * 4 + 0];
        s1 += pm * Wp2[m * 4 + 1];
        s2 += pm * Wp2[m * 4 + 2];
        s3 += pm * Wp2[m * 4 + 3];
    }
    float4 ov; ov.x = s0; ov.y = s1; ov.z = s2; ov.w = s3;
    *reinterpret_cast<float4*>(out + (size_t)i * 4) = ov;
}

// ---------------------------------------------------------------------------
__global__ __launch_bounds__(256) void audit(
    const float* __restrict__ ws, float* __restrict__ out)
{
    __shared__ float red[256];
    const int t = threadIdx.x;
    float mx = 0.0f;
    for (int i = t; i < NROWS * 4; i += 256) {
        float v = ws[WS_GPRE + i];
        if (v != v) mx = 1e30f;
        else mx = fmaxf(mx, fabsf(v));
    }
    red[t] = mx;
    __syncthreads();
    for (int s = 128; s > 0; s >>= 1) {
        if (t < s) red[t] = fmaxf(red[t], red[t + s]);
        __syncthreads();
    }
    const float g = red[0];
    float V = 0.0f;
    if (g >= 1e29f)      V = ldexpf(1.0f, 38);
    else if (g <= 1e-8f) V = ldexpf(1.0f, 36);
    if (V != 0.0f) {
        for (int i = t; i < NROWS * 4; i += 256) out[i] = V;
    }
}

// ---------------------------------------------------------------------------
extern "C" void kernel_launch(void* const* d_in, const int* in_sizes, int n_in,
                              void* d_out, int out_size, void* d_ws, size_t ws_size,
                              hipStream_t stream) {
    float* out = (float*)d_out;
    float* ws  = (float*)d_ws;

    static const int dict_sizes[19] = {32768, 512, 64, 4096, 64, 4096, 64,
                                       1, 3, 1, 3, 1, 256, 64, 1, 2048, 32, 128, 4};
    if (n_in != 19) {
        beacon<<<64, 256, 0, stream>>>(out, ldexpf(1.0f + (float)n_in / 256.0f, 40));
        return;
    }
    bool is_dict = true;
    for (int i = 0; i < 19; ++i) if (in_sizes[i] != dict_sizes[i]) is_dict = false;
    if (!is_dict) {
        beacon<<<64, 256, 0, stream>>>(out, ldexpf(1.0f, 42));
        return;
    }
    if (out_size != NROWS * 4) {
        beacon<<<64, 256, 0, stream>>>(out, ldexpf(1.0f, 44));
        return;
    }
    if (ws_size < (size_t)WS_NEED * sizeof(float)) {
        beacon<<<64, 256, 0, stream>>>(out, ldexpf(1.0f, 46));
        return;
    }

    const float* in   = (const float*)d_in[0];
    const float* We   = (const float*)d_in[1];
    const float* be   = (const float*)d_in[2];
    const float* Wq   = (const float*)d_in[3];
    const float* bq   = (const float*)d_in[4];
    const float* Wk   = (const float*)d_in[5];
    const float* bk   = (const float*)d_in[6];
    const float* pa   = (const float*)d_in[7];
    const float* c1k  = (const float*)d_in[8];
    const float* c1b  = (const float*)d_in[9];
    const float* c2k  = (const float*)d_in[10];
    const float* c2b  = (const float*)d_in[11];
    const float* Wg   = (const float*)d_in[12];
    const float* bg   = (const float*)d_in[13];
    const float* ga   = (const float*)d_in[14];
    const float* Wp1  = (const float*)d_in[15];
    const float* bp1  = (const float*)d_in[16];
    const float* Wp2  = (const float*)d_in[17];
    const float* bp2  = (const float*)d_in[18];

    zero_rs<<<80, 256, 0, stream>>>(ws);
    embed_x<<<1024, 256, 0, stream>>>(in, We, be, ws);
    qk_proj<<<1024, 256, 0, stream>>>(Wq, bq, Wk, bk, ws);

    dim3 gt(64, 64);
    scores_tile<<<gt, 256, 0, stream>>>(ws);
    fused_stencil10<<<gt, 256, 0, stream>>>(c1k, c1b, c2k, c2b, pa, ws);

    dim3 ga2(16, 64);
    adj_me<<<ga2, 256, 0, stream>>>(in, ws);
    head<<<16, 256, 0, stream>>>(ws, Wg, bg, ga, Wp1, bp1, Wp2, bp2, out);
    audit<<<1, 256, 0, stream>>>(ws, out);
}

// Round 14
// 437.805 us; speedup vs baseline: 1.6515x; 1.1364x over previous
//
#include <hip/hip_runtime.h>
#include <math.h>

#define NROWS 4096

// ws float offsets
#define WS_Q    0u          // 4096*64 q
#define WS_K    262144u     // 4096*64 k
#define WS_RS   524288u     // 4096 row sums
#define WS_GPRE 528384u     // 4096*4
#define WS_X    544768u     // 4096*64 embedded x
#define BUFC    1048576u    // 4096*4096 cf5 intermediate (pass1 -> pass2)
#define BUFE    17825792u   // 4096*4096 E scores; pass2 overwrites core with ME
#define WS_NEED 34603008u   // floats = 138.4 MB

static __device__ __forceinline__ float preluf(float x, float a) {
    return x > 0.0f ? x : a * x;
}

// ---------------------------------------------------------------------------
__global__ __launch_bounds__(256) void beacon(float* __restrict__ out, float v) {
    int i = blockIdx.x * 256 + threadIdx.x;
    if (i < NROWS * 4) out[i] = v;
}

__global__ __launch_bounds__(256) void zero_rs(float* __restrict__ ws) {
    int i = blockIdx.x * 256 + threadIdx.x;
    if (i < 20480) ws[WS_RS + i] = 0.0f;
}

// ---------------------------------------------------------------------------
__global__ __launch_bounds__(256) void embed_x(
    const float* __restrict__ in, const float* __restrict__ We,
    const float* __restrict__ be, float* __restrict__ ws)
{
    int gid = blockIdx.x * 256 + threadIdx.x;
    int i = gid >> 6, h = gid & 63;
    float s = be[h];
    #pragma unroll
    for (int d = 0; d < 8; ++d) s += in[(size_t)i * 8 + d] * We[d * 64 + h];
    ws[WS_X + gid] = s;
}

__global__ __launch_bounds__(256) void qk_proj(
    const float* __restrict__ Wq, const float* __restrict__ bq,
    const float* __restrict__ Wk, const float* __restrict__ bk,
    float* __restrict__ ws)
{
    int gid = blockIdx.x * 256 + threadIdx.x;
    int i = gid >> 6, h = gid & 63;
    const float* x = ws + WS_X + (size_t)i * 64;
    float sq = bq[h], sk = bk[h];
    for (int d = 0; d < 64; ++d) {
        float xv = x[d];
        sq += xv * Wq[d * 64 + h];
        sk += xv * Wk[d * 64 + h];
    }
    ws[WS_Q + gid] = sq;
    ws[WS_K + gid] = sk;
}

// ---------------------------------------------------------------------------
__global__ __launch_bounds__(256) void scores_tile(float* __restrict__ ws)
{
    __shared__ float qs[64][65];
    __shared__ float ks[64][65];
    const int br = blockIdx.y * 64, bc = blockIdx.x * 64;
    const int t = threadIdx.x;
    for (int idx = t; idx < 4096; idx += 256) {
        int r = idx >> 6, d = idx & 63;
        qs[r][d] = ws[WS_Q + (size_t)(br + r) * 64 + d];
        ks[r][d] = ws[WS_K + (size_t)(bc + r) * 64 + d];
    }
    __syncthreads();
    const int rg = t >> 6, j = t & 63;
    #pragma unroll 1
    for (int rr = 0; rr < 16; ++rr) {
        const int r = rg * 16 + rr;
        float d = 0.0f;
        #pragma unroll
        for (int dd = 0; dd < 64; ++dd) d += qs[r][dd] * ks[j][dd];
        float e = expf(d * 0.125f);
        ws[BUFE + (size_t)(br + r) * NROWS + bc + j] = e;
        float red = e;
        #pragma unroll
        for (int off = 1; off < 64; off <<= 1) red += __shfl_xor(red, off);
        if (j == 0) atomicAdd(&ws[WS_RS + br + r], red);
    }
}

// ---------------------------------------------------------------------------
// K3a: stencil iterations 1..5 (halo 5, 74x75 LDS, 3 blocks/CU).
// Input: E*il from BUFE (74x74 halo). Output: cf5 64x64 core -> BUFC.
// Interior: column-per-thread rolling sweep, dynamic 3-band row balance,
// cone [it, 73-it]. Edge blocks: scalar path with in-matrix forcing.
// ---------------------------------------------------------------------------
__global__ __launch_bounds__(256) void stencil_p1(
    const float* __restrict__ c1k, const float* __restrict__ c1b,
    const float* __restrict__ c2k, const float* __restrict__ c2b,
    const float* __restrict__ pa, float* __restrict__ ws)
{
    const int bx = blockIdx.x, by = blockIdx.y;
    const int r0 = by * 64, c0t = bx * 64;
    const int t = threadIdx.x;
    __shared__ float buf[2][74][75];
    __shared__ float il_s[74];

    for (int e = t; e < 74; e += 256) {
        int gr = r0 - 5 + e;
        il_s[e] = ((unsigned)gr < (unsigned)NROWS) ? 1.0f / ws[WS_RS + gr] : 0.0f;
    }
    __syncthreads();

    const bool edge = (bx == 0) || (bx == 63) || (by == 0) || (by == 63);

    {   // halo load: fixed col lci = t%74, rows t/74 + 3k (222 active)
        const int lci = t % 74;
        const int lr0 = t / 74;
        if (lr0 < 3) {
            if (!edge) {
                const size_t gbase = BUFE + (size_t)(r0 - 5) * NROWS + (c0t - 5) + lci;
                for (int ri = lr0; ri < 74; ri += 3)
                    buf[0][ri][lci] = ws[gbase + (size_t)ri * NROWS] * il_s[ri];
            } else {
                for (int ri = lr0; ri < 74; ri += 3) {
                    int gr = r0 - 5 + ri, gc = c0t - 5 + lci;
                    float v = 0.0f;
                    if ((unsigned)gr < (unsigned)NROWS && (unsigned)gc < (unsigned)NROWS)
                        v = ws[BUFE + (size_t)gr * NROWS + gc] * il_s[ri];
                    buf[0][ri][lci] = v;
                }
            }
        }
    }
    __syncthreads();

    const float k10 = c1k[0], k11 = c1k[1], k12 = c1k[2];
    const float k20 = c2k[0], k21 = c2k[1], k22 = c2k[2];
    const float bb = c1b[0] + c2b[0];
    const float a = pa[0];

    int cur = 0;
    if (!edge) {
        const int ci = 1 + t % 75;      // 1..75
        const int g  = t / 75;          // 0..3 (3 inactive)
        for (int it = 1; it <= 5; ++it) {
            const int nxt = cur ^ 1;
            if (g < 3 && ci >= it && ci <= 73 - it) {
                const int nr = 74 - 2 * it;
                const int rlo = it + (nr * g) / 3;
                const int rhi = it + (nr * (g + 1)) / 3 - 1;
                float u  = buf[cur][rlo - 1][ci];
                float l  = buf[cur][rlo][ci - 1];
                float c  = buf[cur][rlo][ci];
                float rr = buf[cur][rlo][ci + 1];
                for (int r = rlo; r <= rhi; ++r) {
                    float d = buf[cur][r + 1][ci];
                    float s = k10 * l + k11 * c + k12 * rr + bb +
                              k20 * u + k21 * c + k22 * d;
                    buf[nxt][r][ci] = preluf(s, a);
                    u = c;
                    l = buf[cur][r + 1][ci - 1];
                    rr = buf[cur][r + 1][ci + 1];
                    c = d;
                }
            }
            __syncthreads();
            cur = nxt;
        }
    } else {
        for (int it = 1; it <= 5; ++it) {
            const int nxt = cur ^ 1;
            for (int e = t; e < 72 * 72; e += 256) {
                int ri = 1 + e / 72;
                int ci = 1 + (e - (e / 72) * 72);
                float c_ = buf[cur][ri][ci];
                float lf = buf[cur][ri][ci - 1];
                float rt = buf[cur][ri][ci + 1];
                float up = buf[cur][ri - 1][ci];
                float dn = buf[cur][ri + 1][ci];
                float s = preluf(k10 * lf + k11 * c_ + k12 * rt + bb +
                                 k20 * up + k21 * c_ + k22 * dn, a);
                int gr = r0 - 5 + ri, gc = c0t - 5 + ci;
                bool inm = ((unsigned)gr < (unsigned)NROWS) && ((unsigned)gc < (unsigned)NROWS);
                buf[nxt][ri][ci] = inm ? s : 0.0f;
            }
            __syncthreads();
            cur = nxt;
        }
    }

    // write cf5 core (buffer rows/cols [5,68])
    #pragma unroll
    for (int k2 = 0; k2 < 16; ++k2) {
        int e = k2 * 256 + t;
        int r = e >> 6, c = e & 63;
        ws[BUFC + (size_t)(r0 + r) * NROWS + (c0t + c)] = buf[cur][5 + r][5 + c];
    }
}

// ---------------------------------------------------------------------------
// K3b: stencil iterations 6..10 on cf5 (halo 5), then mask and ME.
// Reads cf5 halo from BUFC, core scores E*il from BUFE; writes
// ME = (sigmoid(cf10)>0.5) ? score : 0 IN-PLACE into BUFE core.
// ---------------------------------------------------------------------------
__global__ __launch_bounds__(256) void stencil_p2(
    const float* __restrict__ c1k, const float* __restrict__ c1b,
    const float* __restrict__ c2k, const float* __restrict__ c2b,
    const float* __restrict__ pa, float* __restrict__ ws)
{
    const int bx = blockIdx.x, by = blockIdx.y;
    const int r0 = by * 64, c0t = bx * 64;
    const int t = threadIdx.x;
    __shared__ float buf[2][74][75];
    __shared__ float il_s[74];

    for (int e = t; e < 74; e += 256) {
        int gr = r0 - 5 + e;
        il_s[e] = ((unsigned)gr < (unsigned)NROWS) ? 1.0f / ws[WS_RS + gr] : 0.0f;
    }
    __syncthreads();

    const bool edge = (bx == 0) || (bx == 63) || (by == 0) || (by == 63);

    {   // halo load of cf5
        const int lci = t % 74;
        const int lr0 = t / 74;
        if (lr0 < 3) {
            if (!edge) {
                const size_t gbase = BUFC + (size_t)(r0 - 5) * NROWS + (c0t - 5) + lci;
                for (int ri = lr0; ri < 74; ri += 3)
                    buf[0][ri][lci] = ws[gbase + (size_t)ri * NROWS];
            } else {
                for (int ri = lr0; ri < 74; ri += 3) {
                    int gr = r0 - 5 + ri, gc = c0t - 5 + lci;
                    float v = 0.0f;
                    if ((unsigned)gr < (unsigned)NROWS && (unsigned)gc < (unsigned)NROWS)
                        v = ws[BUFC + (size_t)gr * NROWS + gc];
                    buf[0][ri][lci] = v;
                }
            }
        }
    }
    __syncthreads();

    // stash normalized core scores
    float sc[16];
    #pragma unroll
    for (int k2 = 0; k2 < 16; ++k2) {
        int e = k2 * 256 + t;
        int r = e >> 6, c = e & 63;
        sc[k2] = ws[BUFE + (size_t)(r0 + r) * NROWS + (c0t + c)] * il_s[5 + r];
    }

    const float k10 = c1k[0], k11 = c1k[1], k12 = c1k[2];
    const float k20 = c2k[0], k21 = c2k[1], k22 = c2k[2];
    const float bb = c1b[0] + c2b[0];
    const float a = pa[0];

    int cur = 0;
    if (!edge) {
        const int ci = 1 + t % 75;
        const int g  = t / 75;
        for (int it = 1; it <= 5; ++it) {
            const int nxt = cur ^ 1;
            if (g < 3 && ci >= it && ci <= 73 - it) {
                const int nr = 74 - 2 * it;
                const int rlo = it + (nr * g) / 3;
                const int rhi = it + (nr * (g + 1)) / 3 - 1;
                float u  = buf[cur][rlo - 1][ci];
                float l  = buf[cur][rlo][ci - 1];
                float c  = buf[cur][rlo][ci];
                float rr = buf[cur][rlo][ci + 1];
                for (int r = rlo; r <= rhi; ++r) {
                    float d = buf[cur][r + 1][ci];
                    float s = k10 * l + k11 * c + k12 * rr + bb +
                              k20 * u + k21 * c + k22 * d;
                    buf[nxt][r][ci] = preluf(s, a);
                    u = c;
                    l = buf[cur][r + 1][ci - 1];
                    rr = buf[cur][r + 1][ci + 1];
                    c = d;
                }
            }
            __syncthreads();
            cur = nxt;
        }
    } else {
        for (int it = 1; it <= 5; ++it) {
            const int nxt = cur ^ 1;
            for (int e = t; e < 72 * 72; e += 256) {
                int ri = 1 + e / 72;
                int ci = 1 + (e - (e / 72) * 72);
                float c_ = buf[cur][ri][ci];
                float lf = buf[cur][ri][ci - 1];
                float rt = buf[cur][ri][ci + 1];
                float up = buf[cur][ri - 1][ci];
                float dn = buf[cur][ri + 1][ci];
                float s = preluf(k10 * lf + k11 * c_ + k12 * rt + bb +
                                 k20 * up + k21 * c_ + k22 * dn, a);
                int gr = r0 - 5 + ri, gc = c0t - 5 + ci;
                bool inm = ((unsigned)gr < (unsigned)NROWS) && ((unsigned)gc < (unsigned)NROWS);
                buf[nxt][ri][ci] = inm ? s : 0.0f;
            }
            __syncthreads();
            cur = nxt;
        }
    }

    // mask + ME write (in-place into BUFE core)
    #pragma unroll
    for (int k2 = 0; k2 < 16; ++k2) {
        int e = k2 * 256 + t;
        int r = e >> 6, c = e & 63;
        float cf = buf[cur][5 + r][5 + c];
        float ex = expf(-cf);
        float sg = 1.0f / (1.0f + ex);
        float me = (sg > 0.5f) ? sc[k2] : 0.0f;
        ws[BUFE + (size_t)(r0 + r) * NROWS + (c0t + c)] = me;
    }
}

// ---------------------------------------------------------------------------
// K4: gpre[i][c] = sum_j ME[i][j] * o[j][c] — streaming reduction over BUFE.
// ---------------------------------------------------------------------------
__global__ __launch_bounds__(256) void adj_me(
    const float* __restrict__ in, float* __restrict__ ws)
{
    const int br = blockIdx.y * 64;
    const int jb = blockIdx.x * 256;
    const int t = threadIdx.x;
    __shared__ float os[64][5];
    const int rg = t >> 6, j = t & 63;

    float a0[16], a1[16], a2[16], a3[16];
    #pragma unroll
    for (int rr = 0; rr < 16; ++rr) { a0[rr]=0.f; a1[rr]=0.f; a2[rr]=0.f; a3[rr]=0.f; }

    for (int ch = 0; ch < 4; ++ch) {
        const int c0 = jb + ch * 64;
        __syncthreads();
        { int jj = t >> 2, c = t & 3; os[jj][c] = in[(size_t)(c0 + jj) * 8 + c]; }
        __syncthreads();
        const int rbase = br + rg * 16;
        #pragma unroll
        for (int rr = 0; rr < 16; ++rr) {
            float me = ws[BUFE + (size_t)(rbase + rr) * NROWS + c0 + j];
            a0[rr] += me * os[j][0];
            a1[rr] += me * os[j][1];
            a2[rr] += me * os[j][2];
            a3[rr] += me * os[j][3];
        }
    }
    #pragma unroll
    for (int rr = 0; rr < 16; ++rr) {
        float v0 = a0[rr], v1 = a1[rr], v2 = a2[rr], v3 = a3[rr];
        #pragma unroll
        for (int off = 1; off < 64; off <<= 1) {
            v0 += __shfl_xor(v0, off);
            v1 += __shfl_xor(v1, off);
            v2 += __shfl_xor(v2, off);
            v3 += __shfl_xor(v3, off);
        }
        if (j == 0) {
            const int row = br + rg * 16 + rr;
            atomicAdd(&ws[WS_GPRE + (size_t)row * 4 + 0], v0);
            atomicAdd(&ws[WS_GPRE + (size_t)row * 4 + 1], v1);
            atomicAdd(&ws[WS_GPRE + (size_t)row * 4 + 2], v2);
            atomicAdd(&ws[WS_GPRE + (size_t)row * 4 + 3], v3);
        }
    }
}

// ---------------------------------------------------------------------------
__global__ __launch_bounds__(256) void head(
    const float* __restrict__ ws,
    const float* __restrict__ Wg, const float* __restrict__ bg, const float* __restrict__ ga,
    const float* __restrict__ Wp1, const float* __restrict__ bp1,
    const float* __restrict__ Wp2, const float* __restrict__ bp2,
    float* __restrict__ out)
{
    int i = blockIdx.x * 256 + threadIdx.x;
    if (i >= NROWS) return;
    const float a = ga[0];
    float gp[4];
    #pragma unroll
    for (int c = 0; c < 4; ++c) gp[c] = ws[WS_GPRE + (size_t)i * 4 + c];
    float p1[32];
    #pragma unroll
    for (int m = 0; m < 32; ++m) p1[m] = bp1[m];
    for (int h = 0; h < 64; ++h) {
        float s = bg[h];
        #pragma unroll
        for (int c = 0; c < 4; ++c) s += gp[c] * Wg[c * 64 + h];
        float gh = preluf(s, a);
        #pragma unroll
        for (int m = 0; m < 32; ++m) p1[m] += gh * Wp1[h * 32 + m];
    }
    float s0 = bp2[0], s1 = bp2[1], s2 = bp2[2], s3 = bp2[3];
    #pragma unroll
    for (int m = 0; m < 32; ++m) {
        float pm = fmaxf(p1[m], 0.0f);
        s0 += pm * Wp2[m * 4 + 0];
        s1 += pm * Wp2[m * 4 + 1];
        s2 += pm * Wp2[m * 4 + 2];
        s3 += pm * Wp2[m * 4 + 3];
    }
    float4 ov; ov.x = s0; ov.y = s1; ov.z = s2; ov.w = s3;
    *reinterpret_cast<float4*>(out + (size_t)i * 4) = ov;
}

// ---------------------------------------------------------------------------
__global__ __launch_bounds__(256) void audit(
    const float* __restrict__ ws, float* __restrict__ out)
{
    __shared__ float red[256];
    const int t = threadIdx.x;
    float mx = 0.0f;
    for (int i = t; i < NROWS * 4; i += 256) {
        float v = ws[WS_GPRE + i];
        if (v != v) mx = 1e30f;
        else mx = fmaxf(mx, fabsf(v));
    }
    red[t] = mx;
    __syncthreads();
    for (int s = 128; s > 0; s >>= 1) {
        if (t < s) red[t] = fmaxf(red[t], red[t + s]);
        __syncthreads();
    }
    const float g = red[0];
    float V = 0.0f;
    if (g >= 1e29f)      V = ldexpf(1.0f, 38);
    else if (g <= 1e-8f) V = ldexpf(1.0f, 36);
    if (V != 0.0f) {
        for (int i = t; i < NROWS * 4; i += 256) out[i] = V;
    }
}

// ---------------------------------------------------------------------------
extern "C" void kernel_launch(void* const* d_in, const int* in_sizes, int n_in,
                              void* d_out, int out_size, void* d_ws, size_t ws_size,
                              hipStream_t stream) {
    float* out = (float*)d_out;
    float* ws  = (float*)d_ws;

    static const int dict_sizes[19] = {32768, 512, 64, 4096, 64, 4096, 64,
                                       1, 3, 1, 3, 1, 256, 64, 1, 2048, 32, 128, 4};
    if (n_in != 19) {
        beacon<<<64, 256, 0, stream>>>(out, ldexpf(1.0f + (float)n_in / 256.0f, 40));
        return;
    }
    bool is_dict = true;
    for (int i = 0; i < 19; ++i) if (in_sizes[i] != dict_sizes[i]) is_dict = false;
    if (!is_dict) {
        beacon<<<64, 256, 0, stream>>>(out, ldexpf(1.0f, 42));
        return;
    }
    if (out_size != NROWS * 4) {
        beacon<<<64, 256, 0, stream>>>(out, ldexpf(1.0f, 44));
        return;
    }
    if (ws_size < (size_t)WS_NEED * sizeof(float)) {
        beacon<<<64, 256, 0, stream>>>(out, ldexpf(1.0f, 46));
        return;
    }

    const float* in   = (const float*)d_in[0];
    const float* We   = (const float*)d_in[1];
    const float* be   = (const float*)d_in[2];
    const float* Wq   = (const float*)d_in[3];
    const float* bq   = (const float*)d_in[4];
    const float* Wk   = (const float*)d_in[5];
    const float* bk   = (const float*)d_in[6];
    const float* pa   = (const float*)d_in[7];
    const float* c1k  = (const float*)d_in[8];
    const float* c1b  = (const float*)d_in[9];
    const float* c2k  = (const float*)d_in[10];
    const float* c2b  = (const float*)d_in[11];
    const float* Wg   = (const float*)d_in[12];
    const float* bg   = (const float*)d_in[13];
    const float* ga   = (const float*)d_in[14];
    const float* Wp1  = (const float*)d_in[15];
    const float* bp1  = (const float*)d_in[16];
    const float* Wp2  = (const float*)d_in[17];
    const float* bp2  = (const float*)d_in[18];

    zero_rs<<<80, 256, 0, stream>>>(ws);
    embed_x<<<1024, 256, 0, stream>>>(in, We, be, ws);
    qk_proj<<<1024, 256, 0, stream>>>(Wq, bq, Wk, bk, ws);

    dim3 gt(64, 64);
    scores_tile<<<gt, 256, 0, stream>>>(ws);
    stencil_p1<<<gt, 256, 0, stream>>>(c1k, c1b, c2k, c2b, pa, ws);
    stencil_p2<<<gt, 256, 0, stream>>>(c1k, c1b, c2k, c2b, pa, ws);

    dim3 ga2(16, 64);
    adj_me<<<ga2, 256, 0, stream>>>(in, ws);
    head<<<16, 256, 0, stream>>>(ws, Wg, bg, ga, Wp1, bp1, Wp2, bp2, out);
    audit<<<1, 256, 0, stream>>>(ws, out);
}

// Round 15
// 373.547 us; speedup vs baseline: 1.9356x; 1.1720x over previous
//
#include <hip/hip_runtime.h>
#include <math.h>

#define NROWS 4096

// ws float offsets
#define WS_Q    0u          // 4096*64 q
#define WS_K    262144u     // 4096*64 k
#define WS_RS   524288u     // 4096 row sums
#define WS_GPRE 528384u     // 4096*4
#define WS_X    544768u     // 4096*64 embedded x
#define BUFC    1048576u    // 4096*4096 cf5 intermediate (pass1 -> pass2)
#define BUFE    17825792u   // 4096*4096 E scores; pass2 overwrites core with ME
#define WS_NEED 34603008u   // floats = 138.4 MB

static __device__ __forceinline__ float preluf(float x, float a) {
    return x > 0.0f ? x : a * x;
}

// ---------------------------------------------------------------------------
__global__ __launch_bounds__(256) void beacon(float* __restrict__ out, float v) {
    int i = blockIdx.x * 256 + threadIdx.x;
    if (i < NROWS * 4) out[i] = v;
}

__global__ __launch_bounds__(256) void zero_rs(float* __restrict__ ws) {
    int i = blockIdx.x * 256 + threadIdx.x;
    if (i < 20480) ws[WS_RS + i] = 0.0f;
}

// ---------------------------------------------------------------------------
__global__ __launch_bounds__(256) void embed_x(
    const float* __restrict__ in, const float* __restrict__ We,
    const float* __restrict__ be, float* __restrict__ ws)
{
    int gid = blockIdx.x * 256 + threadIdx.x;
    int i = gid >> 6, h = gid & 63;
    float s = be[h];
    #pragma unroll
    for (int d = 0; d < 8; ++d) s += in[(size_t)i * 8 + d] * We[d * 64 + h];
    ws[WS_X + gid] = s;
}

__global__ __launch_bounds__(256) void qk_proj(
    const float* __restrict__ Wq, const float* __restrict__ bq,
    const float* __restrict__ Wk, const float* __restrict__ bk,
    float* __restrict__ ws)
{
    int gid = blockIdx.x * 256 + threadIdx.x;
    int i = gid >> 6, h = gid & 63;
    const float* x = ws + WS_X + (size_t)i * 64;
    float sq = bq[h], sk = bk[h];
    for (int d = 0; d < 64; ++d) {
        float xv = x[d];
        sq += xv * Wq[d * 64 + h];
        sk += xv * Wk[d * 64 + h];
    }
    ws[WS_Q + gid] = sq;
    ws[WS_K + gid] = sk;
}

// ---------------------------------------------------------------------------
// K2: 64x64 E-tiles, register-blocked 4x4 per thread, float4 LDS reads.
// Per-output dd-accumulation order is ascending (bit-identical dots to the
// scalar version). ksT staged transposed for aligned float4 column reads.
// ---------------------------------------------------------------------------
__global__ __launch_bounds__(256) void scores_tile(float* __restrict__ ws)
{
    __shared__ float qs[64][68];    // qs[r][dd]
    __shared__ float ksT[64][68];   // ksT[dd][j]
    const int br = blockIdx.y * 64, bc = blockIdx.x * 64;
    const int t = threadIdx.x;

    for (int idx = t; idx < 4096; idx += 256) {
        int r = idx >> 6, d = idx & 63;
        qs[r][d]  = ws[WS_Q + (size_t)(br + r) * 64 + d];
        ksT[d][r] = ws[WS_K + (size_t)(bc + r) * 64 + d];
    }
    __syncthreads();

    const int tr = t >> 4;          // row group 0..15
    const int tc = t & 15;          // col group 0..15
    const int r0 = tr * 4, c0 = tc * 4;

    float acc[4][4];
    #pragma unroll
    for (int i = 0; i < 4; ++i)
        #pragma unroll
        for (int j = 0; j < 4; ++j) acc[i][j] = 0.0f;

    #pragma unroll 4
    for (int dd = 0; dd < 64; dd += 4) {
        float4 qv0 = *reinterpret_cast<const float4*>(&qs[r0 + 0][dd]);
        float4 qv1 = *reinterpret_cast<const float4*>(&qs[r0 + 1][dd]);
        float4 qv2 = *reinterpret_cast<const float4*>(&qs[r0 + 2][dd]);
        float4 qv3 = *reinterpret_cast<const float4*>(&qs[r0 + 3][dd]);
        float4 kv0 = *reinterpret_cast<const float4*>(&ksT[dd + 0][c0]);
        float4 kv1 = *reinterpret_cast<const float4*>(&ksT[dd + 1][c0]);
        float4 kv2 = *reinterpret_cast<const float4*>(&ksT[dd + 2][c0]);
        float4 kv3 = *reinterpret_cast<const float4*>(&ksT[dd + 3][c0]);
        #pragma unroll
        for (int i = 0; i < 4; ++i) {
            const float4 qv = (i == 0) ? qv0 : (i == 1) ? qv1 : (i == 2) ? qv2 : qv3;
            acc[i][0] += qv.x * kv0.x; acc[i][1] += qv.x * kv0.y;
            acc[i][2] += qv.x * kv0.z; acc[i][3] += qv.x * kv0.w;
            acc[i][0] += qv.y * kv1.x; acc[i][1] += qv.y * kv1.y;
            acc[i][2] += qv.y * kv1.z; acc[i][3] += qv.y * kv1.w;
            acc[i][0] += qv.z * kv2.x; acc[i][1] += qv.z * kv2.y;
            acc[i][2] += qv.z * kv2.z; acc[i][3] += qv.z * kv2.w;
            acc[i][0] += qv.w * kv3.x; acc[i][1] += qv.w * kv3.y;
            acc[i][2] += qv.w * kv3.z; acc[i][3] += qv.w * kv3.w;
        }
    }

    #pragma unroll
    for (int i = 0; i < 4; ++i) {
        const int r = r0 + i;
        float4 ev;
        ev.x = expf(acc[i][0] * 0.125f);
        ev.y = expf(acc[i][1] * 0.125f);
        ev.z = expf(acc[i][2] * 0.125f);
        ev.w = expf(acc[i][3] * 0.125f);
        float rs = (ev.x + ev.y) + (ev.z + ev.w);
        #pragma unroll
        for (int off = 1; off < 16; off <<= 1) rs += __shfl_xor(rs, off);
        if (tc == 0) atomicAdd(&ws[WS_RS + br + r], rs);
        *reinterpret_cast<float4*>(&ws[BUFE + (size_t)(br + r) * NROWS + bc + c0]) = ev;
    }
}

// ---------------------------------------------------------------------------
// K3a: stencil iterations 1..5 (halo 5, 74x75 LDS, 3 blocks/CU).
// ---------------------------------------------------------------------------
__global__ __launch_bounds__(256) void stencil_p1(
    const float* __restrict__ c1k, const float* __restrict__ c1b,
    const float* __restrict__ c2k, const float* __restrict__ c2b,
    const float* __restrict__ pa, float* __restrict__ ws)
{
    const int bx = blockIdx.x, by = blockIdx.y;
    const int r0 = by * 64, c0t = bx * 64;
    const int t = threadIdx.x;
    __shared__ float buf[2][74][75];
    __shared__ float il_s[74];

    for (int e = t; e < 74; e += 256) {
        int gr = r0 - 5 + e;
        il_s[e] = ((unsigned)gr < (unsigned)NROWS) ? 1.0f / ws[WS_RS + gr] : 0.0f;
    }
    __syncthreads();

    const bool edge = (bx == 0) || (bx == 63) || (by == 0) || (by == 63);

    {
        const int lci = t % 74;
        const int lr0 = t / 74;
        if (lr0 < 3) {
            if (!edge) {
                const size_t gbase = BUFE + (size_t)(r0 - 5) * NROWS + (c0t - 5) + lci;
                for (int ri = lr0; ri < 74; ri += 3)
                    buf[0][ri][lci] = ws[gbase + (size_t)ri * NROWS] * il_s[ri];
            } else {
                for (int ri = lr0; ri < 74; ri += 3) {
                    int gr = r0 - 5 + ri, gc = c0t - 5 + lci;
                    float v = 0.0f;
                    if ((unsigned)gr < (unsigned)NROWS && (unsigned)gc < (unsigned)NROWS)
                        v = ws[BUFE + (size_t)gr * NROWS + gc] * il_s[ri];
                    buf[0][ri][lci] = v;
                }
            }
        }
    }
    __syncthreads();

    const float k10 = c1k[0], k11 = c1k[1], k12 = c1k[2];
    const float k20 = c2k[0], k21 = c2k[1], k22 = c2k[2];
    const float bb = c1b[0] + c2b[0];
    const float a = pa[0];

    int cur = 0;
    if (!edge) {
        const int ci = 1 + t % 75;
        const int g  = t / 75;
        for (int it = 1; it <= 5; ++it) {
            const int nxt = cur ^ 1;
            if (g < 3 && ci >= it && ci <= 73 - it) {
                const int nr = 74 - 2 * it;
                const int rlo = it + (nr * g) / 3;
                const int rhi = it + (nr * (g + 1)) / 3 - 1;
                float u  = buf[cur][rlo - 1][ci];
                float l  = buf[cur][rlo][ci - 1];
                float c  = buf[cur][rlo][ci];
                float rr = buf[cur][rlo][ci + 1];
                for (int r = rlo; r <= rhi; ++r) {
                    float d = buf[cur][r + 1][ci];
                    float s = k10 * l + k11 * c + k12 * rr + bb +
                              k20 * u + k21 * c + k22 * d;
                    buf[nxt][r][ci] = preluf(s, a);
                    u = c;
                    l = buf[cur][r + 1][ci - 1];
                    rr = buf[cur][r + 1][ci + 1];
                    c = d;
                }
            }
            __syncthreads();
            cur = nxt;
        }
    } else {
        for (int it = 1; it <= 5; ++it) {
            const int nxt = cur ^ 1;
            for (int e = t; e < 72 * 72; e += 256) {
                int ri = 1 + e / 72;
                int ci = 1 + (e - (e / 72) * 72);
                float c_ = buf[cur][ri][ci];
                float lf = buf[cur][ri][ci - 1];
                float rt = buf[cur][ri][ci + 1];
                float up = buf[cur][ri - 1][ci];
                float dn = buf[cur][ri + 1][ci];
                float s = preluf(k10 * lf + k11 * c_ + k12 * rt + bb +
                                 k20 * up + k21 * c_ + k22 * dn, a);
                int gr = r0 - 5 + ri, gc = c0t - 5 + ci;
                bool inm = ((unsigned)gr < (unsigned)NROWS) && ((unsigned)gc < (unsigned)NROWS);
                buf[nxt][ri][ci] = inm ? s : 0.0f;
            }
            __syncthreads();
            cur = nxt;
        }
    }

    #pragma unroll
    for (int k2 = 0; k2 < 16; ++k2) {
        int e = k2 * 256 + t;
        int r = e >> 6, c = e & 63;
        ws[BUFC + (size_t)(r0 + r) * NROWS + (c0t + c)] = buf[cur][5 + r][5 + c];
    }
}

// ---------------------------------------------------------------------------
// K3b: stencil iterations 6..10 on cf5 (halo 5), then mask and ME (in-place).
// ---------------------------------------------------------------------------
__global__ __launch_bounds__(256) void stencil_p2(
    const float* __restrict__ c1k, const float* __restrict__ c1b,
    const float* __restrict__ c2k, const float* __restrict__ c2b,
    const float* __restrict__ pa, float* __restrict__ ws)
{
    const int bx = blockIdx.x, by = blockIdx.y;
    const int r0 = by * 64, c0t = bx * 64;
    const int t = threadIdx.x;
    __shared__ float buf[2][74][75];
    __shared__ float il_s[74];

    for (int e = t; e < 74; e += 256) {
        int gr = r0 - 5 + e;
        il_s[e] = ((unsigned)gr < (unsigned)NROWS) ? 1.0f / ws[WS_RS + gr] : 0.0f;
    }
    __syncthreads();

    const bool edge = (bx == 0) || (bx == 63) || (by == 0) || (by == 63);

    {
        const int lci = t % 74;
        const int lr0 = t / 74;
        if (lr0 < 3) {
            if (!edge) {
                const size_t gbase = BUFC + (size_t)(r0 - 5) * NROWS + (c0t - 5) + lci;
                for (int ri = lr0; ri < 74; ri += 3)
                    buf[0][ri][lci] = ws[gbase + (size_t)ri * NROWS];
            } else {
                for (int ri = lr0; ri < 74; ri += 3) {
                    int gr = r0 - 5 + ri, gc = c0t - 5 + lci;
                    float v = 0.0f;
                    if ((unsigned)gr < (unsigned)NROWS && (unsigned)gc < (unsigned)NROWS)
                        v = ws[BUFC + (size_t)gr * NROWS + gc];
                    buf[0][ri][lci] = v;
                }
            }
        }
    }
    __syncthreads();

    float sc[16];
    #pragma unroll
    for (int k2 = 0; k2 < 16; ++k2) {
        int e = k2 * 256 + t;
        int r = e >> 6, c = e & 63;
        sc[k2] = ws[BUFE + (size_t)(r0 + r) * NROWS + (c0t + c)] * il_s[5 + r];
    }

    const float k10 = c1k[0], k11 = c1k[1], k12 = c1k[2];
    const float k20 = c2k[0], k21 = c2k[1], k22 = c2k[2];
    const float bb = c1b[0] + c2b[0];
    const float a = pa[0];

    int cur = 0;
    if (!edge) {
        const int ci = 1 + t % 75;
        const int g  = t / 75;
        for (int it = 1; it <= 5; ++it) {
            const int nxt = cur ^ 1;
            if (g < 3 && ci >= it && ci <= 73 - it) {
                const int nr = 74 - 2 * it;
                const int rlo = it + (nr * g) / 3;
                const int rhi = it + (nr * (g + 1)) / 3 - 1;
                float u  = buf[cur][rlo - 1][ci];
                float l  = buf[cur][rlo][ci - 1];
                float c  = buf[cur][rlo][ci];
                float rr = buf[cur][rlo][ci + 1];
                for (int r = rlo; r <= rhi; ++r) {
                    float d = buf[cur][r + 1][ci];
                    float s = k10 * l + k11 * c + k12 * rr + bb +
                              k20 * u + k21 * c + k22 * d;
                    buf[nxt][r][ci] = preluf(s, a);
                    u = c;
                    l = buf[cur][r + 1][ci - 1];
                    rr = buf[cur][r + 1][ci + 1];
                    c = d;
                }
            }
            __syncthreads();
            cur = nxt;
        }
    } else {
        for (int it = 1; it <= 5; ++it) {
            const int nxt = cur ^ 1;
            for (int e = t; e < 72 * 72; e += 256) {
                int ri = 1 + e / 72;
                int ci = 1 + (e - (e / 72) * 72);
                float c_ = buf[cur][ri][ci];
                float lf = buf[cur][ri][ci - 1];
                float rt = buf[cur][ri][ci + 1];
                float up = buf[cur][ri - 1][ci];
                float dn = buf[cur][ri + 1][ci];
                float s = preluf(k10 * lf + k11 * c_ + k12 * rt + bb +
                                 k20 * up + k21 * c_ + k22 * dn, a);
                int gr = r0 - 5 + ri, gc = c0t - 5 + ci;
                bool inm = ((unsigned)gr < (unsigned)NROWS) && ((unsigned)gc < (unsigned)NROWS);
                buf[nxt][ri][ci] = inm ? s : 0.0f;
            }
            __syncthreads();
            cur = nxt;
        }
    }

    #pragma unroll
    for (int k2 = 0; k2 < 16; ++k2) {
        int e = k2 * 256 + t;
        int r = e >> 6, c = e & 63;
        float cf = buf[cur][5 + r][5 + c];
        float ex = expf(-cf);
        float sg = 1.0f / (1.0f + ex);
        float me = (sg > 0.5f) ? sc[k2] : 0.0f;
        ws[BUFE + (size_t)(r0 + r) * NROWS + (c0t + c)] = me;
    }
}

// ---------------------------------------------------------------------------
// K4: gpre[i][c] = sum_j ME[i][j] * o[j][c] — streaming reduction over BUFE.
// ---------------------------------------------------------------------------
__global__ __launch_bounds__(256) void adj_me(
    const float* __restrict__ in, float* __restrict__ ws)
{
    const int br = blockIdx.y * 64;
    const int jb = blockIdx.x * 256;
    const int t = threadIdx.x;
    __shared__ float os[64][5];
    const int rg = t >> 6, j = t & 63;

    float a0[16], a1[16], a2[16], a3[16];
    #pragma unroll
    for (int rr = 0; rr < 16; ++rr) { a0[rr]=0.f; a1[rr]=0.f; a2[rr]=0.f; a3[rr]=0.f; }

    for (int ch = 0; ch < 4; ++ch) {
        const int c0 = jb + ch * 64;
        __syncthreads();
        { int jj = t >> 2, c = t & 3; os[jj][c] = in[(size_t)(c0 + jj) * 8 + c]; }
        __syncthreads();
        const int rbase = br + rg * 16;
        #pragma unroll
        for (int rr = 0; rr < 16; ++rr) {
            float me = ws[BUFE + (size_t)(rbase + rr) * NROWS + c0 + j];
            a0[rr] += me * os[j][0];
            a1[rr] += me * os[j][1];
            a2[rr] += me * os[j][2];
            a3[rr] += me * os[j][3];
        }
    }
    #pragma unroll
    for (int rr = 0; rr < 16; ++rr) {
        float v0 = a0[rr], v1 = a1[rr], v2 = a2[rr], v3 = a3[rr];
        #pragma unroll
        for (int off = 1; off < 64; off <<= 1) {
            v0 += __shfl_xor(v0, off);
            v1 += __shfl_xor(v1, off);
            v2 += __shfl_xor(v2, off);
            v3 += __shfl_xor(v3, off);
        }
        if (j == 0) {
            const int row = br + rg * 16 + rr;
            atomicAdd(&ws[WS_GPRE + (size_t)row * 4 + 0], v0);
            atomicAdd(&ws[WS_GPRE + (size_t)row * 4 + 1], v1);
            atomicAdd(&ws[WS_GPRE + (size_t)row * 4 + 2], v2);
            atomicAdd(&ws[WS_GPRE + (size_t)row * 4 + 3], v3);
        }
    }
}

// ---------------------------------------------------------------------------
__global__ __launch_bounds__(256) void head(
    const float* __restrict__ ws,
    const float* __restrict__ Wg, const float* __restrict__ bg, const float* __restrict__ ga,
    const float* __restrict__ Wp1, const float* __restrict__ bp1,
    const float* __restrict__ Wp2, const float* __restrict__ bp2,
    float* __restrict__ out)
{
    int i = blockIdx.x * 256 + threadIdx.x;
    if (i >= NROWS) return;
    const float a = ga[0];
    float gp[4];
    #pragma unroll
    for (int c = 0; c < 4; ++c) gp[c] = ws[WS_GPRE + (size_t)i * 4 + c];
    float p1[32];
    #pragma unroll
    for (int m = 0; m < 32; ++m) p1[m] = bp1[m];
    for (int h = 0; h < 64; ++h) {
        float s = bg[h];
        #pragma unroll
        for (int c = 0; c < 4; ++c) s += gp[c] * Wg[c * 64 + h];
        float gh = preluf(s, a);
        #pragma unroll
        for (int m = 0; m < 32; ++m) p1[m] += gh * Wp1[h * 32 + m];
    }
    float s0 = bp2[0], s1 = bp2[1], s2 = bp2[2], s3 = bp2[3];
    #pragma unroll
    for (int m = 0; m < 32; ++m) {
        float pm = fmaxf(p1[m], 0.0f);
        s0 += pm * Wp2[m * 4 + 0];
        s1 += pm * Wp2[m * 4 + 1];
        s2 += pm * Wp2[m * 4 + 2];
        s3 += pm * Wp2[m * 4 + 3];
    }
    float4 ov; ov.x = s0; ov.y = s1; ov.z = s2; ov.w = s3;
    *reinterpret_cast<float4*>(out + (size_t)i * 4) = ov;
}

// ---------------------------------------------------------------------------
__global__ __launch_bounds__(256) void audit(
    const float* __restrict__ ws, float* __restrict__ out)
{
    __shared__ float red[256];
    const int t = threadIdx.x;
    float mx = 0.0f;
    for (int i = t; i < NROWS * 4; i += 256) {
        float v = ws[WS_GPRE + i];
        if (v != v) mx = 1e30f;
        else mx = fmaxf(mx, fabsf(v));
    }
    red[t] = mx;
    __syncthreads();
    for (int s = 128; s > 0; s >>= 1) {
        if (t < s) red[t] = fmaxf(red[t], red[t + s]);
        __syncthreads();
    }
    const float g = red[0];
    float V = 0.0f;
    if (g >= 1e29f)      V = ldexpf(1.0f, 38);
    else if (g <= 1e-8f) V = ldexpf(1.0f, 36);
    if (V != 0.0f) {
        for (int i = t; i < NROWS * 4; i += 256) out[i] = V;
    }
}

// ---------------------------------------------------------------------------
extern "C" void kernel_launch(void* const* d_in, const int* in_sizes, int n_in,
                              void* d_out, int out_size, void* d_ws, size_t ws_size,
                              hipStream_t stream) {
    float* out = (float*)d_out;
    float* ws  = (float*)d_ws;

    static const int dict_sizes[19] = {32768, 512, 64, 4096, 64, 4096, 64,
                                       1, 3, 1, 3, 1, 256, 64, 1, 2048, 32, 128, 4};
    if (n_in != 19) {
        beacon<<<64, 256, 0, stream>>>(out, ldexpf(1.0f + (float)n_in / 256.0f, 40));
        return;
    }
    bool is_dict = true;
    for (int i = 0; i < 19; ++i) if (in_sizes[i] != dict_sizes[i]) is_dict = false;
    if (!is_dict) {
        beacon<<<64, 256, 0, stream>>>(out, ldexpf(1.0f, 42));
        return;
    }
    if (out_size != NROWS * 4) {
        beacon<<<64, 256, 0, stream>>>(out, ldexpf(1.0f, 44));
        return;
    }
    if (ws_size < (size_t)WS_NEED * sizeof(float)) {
        beacon<<<64, 256, 0, stream>>>(out, ldexpf(1.0f, 46));
        return;
    }

    const float* in   = (const float*)d_in[0];
    const float* We   = (const float*)d_in[1];
    const float* be   = (const float*)d_in[2];
    const float* Wq   = (const float*)d_in[3];
    const float* bq   = (const float*)d_in[4];
    const float* Wk   = (const float*)d_in[5];
    const float* bk   = (const float*)d_in[6];
    const float* pa   = (const float*)d_in[7];
    const float* c1k  = (const float*)d_in[8];
    const float* c1b  = (const float*)d_in[9];
    const float* c2k  = (const float*)d_in[10];
    const float* c2b  = (const float*)d_in[11];
    const float* Wg   = (const float*)d_in[12];
    const float* bg   = (const float*)d_in[13];
    const float* ga   = (const float*)d_in[14];
    const float* Wp1  = (const float*)d_in[15];
    const float* bp1  = (const float*)d_in[16];
    const float* Wp2  = (const float*)d_in[17];
    const float* bp2  = (const float*)d_in[18];

    zero_rs<<<80, 256, 0, stream>>>(ws);
    embed_x<<<1024, 256, 0, stream>>>(in, We, be, ws);
    qk_proj<<<1024, 256, 0, stream>>>(Wq, bq, Wk, bk, ws);

    dim3 gt(64, 64);
    scores_tile<<<gt, 256, 0, stream>>>(ws);
    stencil_p1<<<gt, 256, 0, stream>>>(c1k, c1b, c2k, c2b, pa, ws);
    stencil_p2<<<gt, 256, 0, stream>>>(c1k, c1b, c2k, c2b, pa, ws);

    dim3 ga2(16, 64);
    adj_me<<<ga2, 256, 0, stream>>>(in, ws);
    head<<<16, 256, 0, stream>>>(ws, Wg, bg, ga, Wp1, bp1, Wp2, bp2, out);
    audit<<<1, 256, 0, stream>>>(ws, out);
}